// Round 1
// baseline (9429.742 us; speedup 1.0000x reference)
//
#include <hip/hip_runtime.h>

#define NN   100000   // num_nodes
#define ETY  5        // edge types
#define NE   500000   // edges per type
#define WIN  256
#define WOUT 128
#define CCH  2
#define LAY  2
#define NCLS 3

// ---------------- softmax over edge types for each (layer, channel) ----------------
__global__ void filt_kernel(const float* __restrict__ conv_w, float* __restrict__ filt) {
    int g = threadIdx.x;                 // group = l*C + c, 4 groups
    if (g < LAY * CCH) {
        float m = -1e30f;
        for (int j = 0; j < ETY; ++j) m = fmaxf(m, conv_w[g * ETY + j]);
        float e[ETY], s = 0.f;
        for (int j = 0; j < ETY; ++j) { e[j] = __expf(conv_w[g * ETY + j] - m); s += e[j]; }
        float inv = 1.f / s;
        for (int j = 0; j < ETY; ++j) filt[g * ETY + j] = e[j] * inv;
    }
}

// ---------------- X_[c][n][o] = sum_k X[n][k] * Ws[c][k][o] ----------------
// block = 256 threads -> 2 rows x 128 cols per block
__global__ void proj_kernel(const float* __restrict__ X, const float* __restrict__ Ws,
                            float* __restrict__ Xp) {
    __shared__ float xs[2 * WIN];
    const int tid = threadIdx.x;
    const int c = blockIdx.y;
    const long long n0 = (long long)blockIdx.x * 2;
    const float* Xb = X + n0 * WIN;
    xs[tid]       = Xb[tid];
    xs[tid + 256] = Xb[tid + 256];
    __syncthreads();
    const int o = tid & (WOUT - 1);
    const int r = tid >> 7;
    const float* W  = Ws + (size_t)c * WIN * WOUT + o;
    const float* xr = xs + r * WIN;
    float a0 = 0.f, a1 = 0.f, a2 = 0.f, a3 = 0.f;
    for (int k = 0; k < WIN; k += 4) {
        a0 = fmaf(xr[k + 0], W[(size_t)(k + 0) * WOUT], a0);
        a1 = fmaf(xr[k + 1], W[(size_t)(k + 1) * WOUT], a1);
        a2 = fmaf(xr[k + 2], W[(size_t)(k + 2) * WOUT], a2);
        a3 = fmaf(xr[k + 3], W[(size_t)(k + 3) * WOUT], a3);
    }
    Xp[((size_t)c * NN + n0 + r) * WOUT + o] = (a0 + a1) + (a2 + a3);
}

// ---------------- sparse propagation: H_new[c] += filt[c][j]*ev * H_in[c][col] scattered to row ----------------
// one wave per (edge, channel) unit; lane i handles features [2i, 2i+1]
__global__ void prop_kernel(const float* __restrict__ Hin, float* __restrict__ Hnew,
                            const int* __restrict__ edge_index,
                            const float* __restrict__ edge_value,
                            const float* __restrict__ filt /* [C][ETY] for this layer */) {
    const int lane = threadIdx.x & 63;
    const int wib  = threadIdx.x >> 6;
    const long long nw = (long long)gridDim.x * (blockDim.x >> 6);
    long long wid = (long long)blockIdx.x * (blockDim.x >> 6) + wib;
    const long long total = (long long)ETY * NE * CCH;
    for (long long u = wid; u < total; u += nw) {
        const int c = (int)(u & 1);
        const long long je = u >> 1;
        const int j = (int)(je / NE);
        const int e = (int)(je - (long long)j * NE);
        const int row = edge_index[(size_t)j * 2 * NE + e];
        const int col = edge_index[(size_t)j * 2 * NE + NE + e];
        const float w = filt[c * ETY + j] * edge_value[(size_t)j * NE + e];
        const float2 v = ((const float2*)(Hin + ((size_t)c * NN + col) * WOUT))[lane];
        float* dst = Hnew + ((size_t)c * NN + row) * WOUT + 2 * lane;
        atomicAdd(dst + 0, w * v.x);
        atomicAdd(dst + 1, w * v.y);
    }
}

// ---------------- H1[n][o] = relu(0.1*X_ + 0.9*H)_concat[n][:] @ w1[:, o] + b1[o] ----------------
__global__ void lin1_kernel(const float* __restrict__ Xp, const float* __restrict__ Hf,
                            const float* __restrict__ w1, const float* __restrict__ b1,
                            float* __restrict__ H1) {
    __shared__ float hs[2 * 256];        // 2 rows x 256 concat feats
    const int tid = threadIdx.x;
    const long long n0 = (long long)blockIdx.x * 2;
    for (int f = tid; f < 512; f += 256) {
        int r = f >> 8;
        int k = f & 255;
        int c = k >> 7;
        int d = k & 127;
        size_t idx = ((size_t)c * NN + n0 + r) * WOUT + d;
        float v = 0.1f * Xp[idx] + 0.9f * Hf[idx];
        hs[f] = v > 0.f ? v : 0.f;
    }
    __syncthreads();
    const int o = tid & (WOUT - 1);
    const int r = tid >> 7;
    const float* W  = w1 + o;
    const float* xr = hs + r * 256;
    float a0 = 0.f, a1 = 0.f, a2 = 0.f, a3 = 0.f;
    for (int k = 0; k < 256; k += 4) {
        a0 = fmaf(xr[k + 0], W[(size_t)(k + 0) * WOUT], a0);
        a1 = fmaf(xr[k + 1], W[(size_t)(k + 1) * WOUT], a1);
        a2 = fmaf(xr[k + 2], W[(size_t)(k + 2) * WOUT], a2);
        a3 = fmaf(xr[k + 3], W[(size_t)(k + 3) * WOUT], a3);
    }
    H1[(n0 + r) * WOUT + o] = (a0 + a1) + (a2 + a3) + b1[o];
}

// ---------------- out[n][m] = H1[n][:] @ w2[:, m] + b2[m] ----------------
__global__ void lin2_kernel(const float* __restrict__ H1, const float* __restrict__ w2,
                            const float* __restrict__ b2, float* __restrict__ out) {
    __shared__ float ws[WOUT * NCLS];
    const int tid = threadIdx.x;
    for (int i = tid; i < WOUT * NCLS; i += 256) ws[i] = w2[i];
    __syncthreads();
    const long long n = (long long)blockIdx.x * 256 + tid;
    if (n >= NN) return;
    const float4* h = (const float4*)(H1 + (size_t)n * WOUT);
    float a0 = b2[0], a1 = b2[1], a2 = b2[2];
    for (int k4 = 0; k4 < WOUT / 4; ++k4) {
        float4 v = h[k4];
        int k = k4 * 4;
        a0 += v.x * ws[(k + 0) * 3 + 0] + v.y * ws[(k + 1) * 3 + 0] + v.z * ws[(k + 2) * 3 + 0] + v.w * ws[(k + 3) * 3 + 0];
        a1 += v.x * ws[(k + 0) * 3 + 1] + v.y * ws[(k + 1) * 3 + 1] + v.z * ws[(k + 2) * 3 + 1] + v.w * ws[(k + 3) * 3 + 1];
        a2 += v.x * ws[(k + 0) * 3 + 2] + v.y * ws[(k + 1) * 3 + 2] + v.z * ws[(k + 2) * 3 + 2] + v.w * ws[(k + 3) * 3 + 2];
    }
    out[n * 3 + 0] = a0;
    out[n * 3 + 1] = a1;
    out[n * 3 + 2] = a2;
}

extern "C" void kernel_launch(void* const* d_in, const int* in_sizes, int n_in,
                              void* d_out, int out_size, void* d_ws, size_t ws_size,
                              hipStream_t stream) {
    const int*   edge_index = (const int*)d_in[0];
    const float* edge_value = (const float*)d_in[1];
    const float* X          = (const float*)d_in[2];
    const float* Ws         = (const float*)d_in[3];
    const float* conv_w     = (const float*)d_in[4];
    const float* lin1_w     = (const float*)d_in[5];
    const float* lin1_b     = (const float*)d_in[6];
    const float* lin2_w     = (const float*)d_in[7];
    const float* lin2_b     = (const float*)d_in[8];
    float* out = (float*)d_out;

    float* ws = (float*)d_ws;
    const size_t CN = (size_t)CCH * NN * WOUT;      // 25.6M floats per H buffer
    float* Xp   = ws;                                // [C][N][WOUT]
    float* A    = ws + CN;                           // H after layer 0
    float* B    = ws + 2 * CN;                       // H after layer 1
    float* H1   = ws + 3 * CN;                       // [N][WOUT]
    float* filt = ws + 3 * CN + (size_t)NN * WOUT;   // [L][C][ETY]

    filt_kernel<<<1, 64, 0, stream>>>(conv_w, filt);

    dim3 gp(NN / 2, CCH);
    proj_kernel<<<gp, 256, 0, stream>>>(X, Ws, Xp);

    // layer 0: Xp -> A
    hipMemsetAsync(A, 0, CN * sizeof(float), stream);
    prop_kernel<<<8192, 256, 0, stream>>>(Xp, A, edge_index, edge_value, filt);

    // layer 1: A -> B
    hipMemsetAsync(B, 0, CN * sizeof(float), stream);
    prop_kernel<<<8192, 256, 0, stream>>>(A, B, edge_index, edge_value, filt + CCH * ETY);

    lin1_kernel<<<NN / 2, 256, 0, stream>>>(Xp, B, lin1_w, lin1_b, H1);
    lin2_kernel<<<(NN + 255) / 256, 256, 0, stream>>>(H1, lin2_w, lin2_b, out);
}

// Round 2
// 2570.726 us; speedup vs baseline: 3.6681x; 3.6681x over previous
//
#include <hip/hip_runtime.h>

#define NN   100000   // num_nodes
#define ETY  5        // edge types
#define NE   500000   // edges per type
#define WIN  256
#define WOUT 128
#define CCH  2
#define LAY  2
#define NCLS 3

#define M_BUCKETS (ETY * NN)          // 500000 (j,row) buckets
#define NTOT      (ETY * NE)          // 2500000 edges total
#define SCAN_CHUNK 1024
#define P_BLOCKS  ((M_BUCKETS + SCAN_CHUNK - 1) / SCAN_CHUNK)   // 489

// ---------------- softmax over edge types for each (layer, channel) ----------------
__global__ void filt_kernel(const float* __restrict__ conv_w, float* __restrict__ filt) {
    int g = threadIdx.x;                 // group = l*C + c, 4 groups
    if (g < LAY * CCH) {
        float m = -1e30f;
        for (int j = 0; j < ETY; ++j) m = fmaxf(m, conv_w[g * ETY + j]);
        float e[ETY], s = 0.f;
        for (int j = 0; j < ETY; ++j) { e[j] = __expf(conv_w[g * ETY + j] - m); s += e[j]; }
        float inv = 1.f / s;
        for (int j = 0; j < ETY; ++j) filt[g * ETY + j] = e[j] * inv;
    }
}

// ---------------- X_[c][n][o] = sum_k X[n][k] * Ws[c][k][o] ----------------
__global__ void proj_kernel(const float* __restrict__ X, const float* __restrict__ Ws,
                            float* __restrict__ Xp) {
    __shared__ float xs[2 * WIN];
    const int tid = threadIdx.x;
    const int c = blockIdx.y;
    const long long n0 = (long long)blockIdx.x * 2;
    const float* Xb = X + n0 * WIN;
    xs[tid]       = Xb[tid];
    xs[tid + 256] = Xb[tid + 256];
    __syncthreads();
    const int o = tid & (WOUT - 1);
    const int r = tid >> 7;
    const float* W  = Ws + (size_t)c * WIN * WOUT + o;
    const float* xr = xs + r * WIN;
    float a0 = 0.f, a1 = 0.f, a2 = 0.f, a3 = 0.f;
    for (int k = 0; k < WIN; k += 4) {
        a0 = fmaf(xr[k + 0], W[(size_t)(k + 0) * WOUT], a0);
        a1 = fmaf(xr[k + 1], W[(size_t)(k + 1) * WOUT], a1);
        a2 = fmaf(xr[k + 2], W[(size_t)(k + 2) * WOUT], a2);
        a3 = fmaf(xr[k + 3], W[(size_t)(k + 3) * WOUT], a3);
    }
    Xp[((size_t)c * NN + n0 + r) * WOUT + o] = (a0 + a1) + (a2 + a3);
}

// ---------------- CSR build: count incoming edges per (type, row) ----------------
__global__ void count_kernel(const int* __restrict__ edge_index, int* __restrict__ cnt) {
    int i = blockIdx.x * 256 + threadIdx.x;
    if (i >= NTOT) return;
    int j = i / NE;
    int e = i - j * NE;
    int row = edge_index[(size_t)j * 2 * NE + e];
    atomicAdd(&cnt[j * NN + row], 1);
}

// partial sums of 1024-chunks
__global__ void scan1_kernel(const int* __restrict__ cnt, int* __restrict__ part) {
    __shared__ int sm[256];
    int b = blockIdx.x, t = threadIdx.x;
    int i0 = b * SCAN_CHUNK;
    int s = 0;
    for (int k = t; k < SCAN_CHUNK; k += 256) {
        int i = i0 + k;
        if (i < M_BUCKETS) s += cnt[i];
    }
    sm[t] = s;
    __syncthreads();
    for (int off = 128; off > 0; off >>= 1) {
        if (t < off) sm[t] += sm[t + off];
        __syncthreads();
    }
    if (t == 0) part[b] = sm[0];
}

// in-place exclusive scan of P_BLOCKS partials (single block)
__global__ void scan2_kernel(int* __restrict__ part) {
    __shared__ int sm[512];
    int t = threadIdx.x;
    for (int k = t; k < P_BLOCKS; k += 256) sm[k] = part[k];
    __syncthreads();
    if (t == 0) {
        int run = 0;
        for (int p = 0; p < P_BLOCKS; ++p) { int v = sm[p]; sm[p] = run; run += v; }
    }
    __syncthreads();
    for (int k = t; k < P_BLOCKS; k += 256) part[k] = sm[k];
}

// per-chunk exclusive scan + chunk base -> base[]
__global__ void scan3_kernel(const int* __restrict__ cnt, const int* __restrict__ part,
                             int* __restrict__ base) {
    __shared__ int wsum[4];
    int b = blockIdx.x, t = threadIdx.x;
    int i0 = b * SCAN_CHUNK + t * 4;
    int v0 = (i0 + 0 < M_BUCKETS) ? cnt[i0 + 0] : 0;
    int v1 = (i0 + 1 < M_BUCKETS) ? cnt[i0 + 1] : 0;
    int v2 = (i0 + 2 < M_BUCKETS) ? cnt[i0 + 2] : 0;
    int v3 = (i0 + 3 < M_BUCKETS) ? cnt[i0 + 3] : 0;
    int s = v0 + v1 + v2 + v3;
    int lane = t & 63;
    int x = s;
    for (int off = 1; off < 64; off <<= 1) {
        int y = __shfl_up(x, off);
        if (lane >= off) x += y;
    }
    if (lane == 63) wsum[t >> 6] = x;
    __syncthreads();
    int wb = 0;
    for (int k = 0; k < (t >> 6); ++k) wb += wsum[k];
    int excl = wb + x - s + part[b];
    if (i0 + 0 < M_BUCKETS) base[i0 + 0] = excl;
    if (i0 + 1 < M_BUCKETS) base[i0 + 1] = excl + v0;
    if (i0 + 2 < M_BUCKETS) base[i0 + 2] = excl + v0 + v1;
    if (i0 + 3 < M_BUCKETS) base[i0 + 3] = excl + v0 + v1 + v2;
}

// scatter edges into CSR slots
__global__ void fill_kernel(const int* __restrict__ edge_index, const float* __restrict__ edge_value,
                            const int* __restrict__ base, int* __restrict__ cur,
                            int* __restrict__ scol, float* __restrict__ sval) {
    int i = blockIdx.x * 256 + threadIdx.x;
    if (i >= NTOT) return;
    int j = i / NE;
    int e = i - j * NE;
    int row = edge_index[(size_t)j * 2 * NE + e];
    int col = edge_index[(size_t)j * 2 * NE + NE + e];
    int idx = j * NN + row;
    int pos = base[idx] + atomicAdd(&cur[idx], 1);
    scol[pos] = col;
    sval[pos] = edge_value[(size_t)j * NE + e];
}

// ---------------- gather propagation: one wave per (node, channel) ----------------
__global__ void gather_kernel(const float* __restrict__ Hin, float* __restrict__ Hnew,
                              const int* __restrict__ base, const int* __restrict__ cnt,
                              const int* __restrict__ scol, const float* __restrict__ sval,
                              const float* __restrict__ filt /* [C][ETY] this layer */) {
    const int lane = threadIdx.x & 63;
    const int wib  = threadIdx.x >> 6;
    const int u = blockIdx.x * 4 + wib;          // (n,c) unit
    if (u >= NN * CCH) return;
    const int c = u & 1;
    const int n = u >> 1;
    const float* Hc = Hin + (size_t)c * NN * WOUT;
    float ax = 0.f, ay = 0.f;
    for (int j = 0; j < ETY; ++j) {
        const float wj = filt[c * ETY + j];
        const int idx = j * NN + n;
        const int s = base[idx];
        const int e = s + cnt[idx];
        for (int k = s; k < e; ++k) {
            const int col = scol[k];
            const float w = wj * sval[k];
            const float2 v = ((const float2*)(Hc + (size_t)col * WOUT))[lane];
            ax = fmaf(w, v.x, ax);
            ay = fmaf(w, v.y, ay);
        }
    }
    float2 r; r.x = ax; r.y = ay;
    ((float2*)(Hnew + ((size_t)c * NN + n) * WOUT))[lane] = r;
}

// ---------------- fused: relu(0.1*Xp + 0.9*Hf) concat -> @w1+b1 -> @w2+b2 -> out ----------------
__global__ void lin_kernel(const float* __restrict__ Xp, const float* __restrict__ Hf,
                           const float* __restrict__ w1, const float* __restrict__ b1,
                           const float* __restrict__ w2, const float* __restrict__ b2,
                           float* __restrict__ out) {
    __shared__ float hs[2 * 256];        // 2 rows x 256 concat feats
    __shared__ float osum[2][NCLS];
    const int tid = threadIdx.x;
    const long long n0 = (long long)blockIdx.x * 2;
    for (int f = tid; f < 512; f += 256) {
        int r = f >> 8;
        int k = f & 255;
        int c = k >> 7;
        int d = k & 127;
        size_t idx = ((size_t)c * NN + n0 + r) * WOUT + d;
        float v = 0.1f * Xp[idx] + 0.9f * Hf[idx];
        hs[f] = v > 0.f ? v : 0.f;
    }
    if (tid < 2 * NCLS) ((float*)osum)[tid] = 0.f;
    __syncthreads();
    const int o = tid & (WOUT - 1);
    const int r = tid >> 7;
    const float* W  = w1 + o;
    const float* xr = hs + r * 256;
    float a0 = 0.f, a1 = 0.f, a2 = 0.f, a3 = 0.f;
    for (int k = 0; k < 256; k += 4) {
        a0 = fmaf(xr[k + 0], W[(size_t)(k + 0) * WOUT], a0);
        a1 = fmaf(xr[k + 1], W[(size_t)(k + 1) * WOUT], a1);
        a2 = fmaf(xr[k + 2], W[(size_t)(k + 2) * WOUT], a2);
        a3 = fmaf(xr[k + 3], W[(size_t)(k + 3) * WOUT], a3);
    }
    const float h1 = (a0 + a1) + (a2 + a3) + b1[o];
    for (int m = 0; m < NCLS; ++m) {
        float p = h1 * w2[o * NCLS + m];
        for (int off = 32; off > 0; off >>= 1) p += __shfl_down(p, off);
        if ((tid & 63) == 0) atomicAdd(&osum[r][m], p);
    }
    __syncthreads();
    if (tid < 2 * NCLS) {
        int rr = tid / NCLS, mm = tid - rr * NCLS;
        out[(n0 + rr) * NCLS + mm] = osum[rr][mm] + b2[mm];
    }
}

extern "C" void kernel_launch(void* const* d_in, const int* in_sizes, int n_in,
                              void* d_out, int out_size, void* d_ws, size_t ws_size,
                              hipStream_t stream) {
    const int*   edge_index = (const int*)d_in[0];
    const float* edge_value = (const float*)d_in[1];
    const float* X          = (const float*)d_in[2];
    const float* Ws         = (const float*)d_in[3];
    const float* conv_w     = (const float*)d_in[4];
    const float* lin1_w     = (const float*)d_in[5];
    const float* lin1_b     = (const float*)d_in[6];
    const float* lin2_w     = (const float*)d_in[7];
    const float* lin2_b     = (const float*)d_in[8];
    float* out = (float*)d_out;

    float* ws = (float*)d_ws;
    const size_t CN = (size_t)CCH * NN * WOUT;       // 25.6M floats per H buffer
    float* Xp   = ws;                                 // [C][N][WOUT]
    float* A    = Xp + CN;                            // H after layer 0
    float* B    = A + CN;                             // H after layer 1
    float* filt = B + CN;                             // [L][C][ETY] (pad to 32)
    int*   cnt  = (int*)(filt + 32);                  // [M_BUCKETS]
    int*   base = cnt + M_BUCKETS;                    // [M_BUCKETS]
    int*   cur  = base + M_BUCKETS;                   // [M_BUCKETS]
    int*   part = cur + M_BUCKETS;                    // [512]
    int*   scol = part + 512;                         // [NTOT]
    float* sval = (float*)(scol + NTOT);              // [NTOT]

    hipMemsetAsync(cnt, 0, M_BUCKETS * sizeof(int), stream);
    hipMemsetAsync(cur, 0, M_BUCKETS * sizeof(int), stream);

    filt_kernel<<<1, 64, 0, stream>>>(conv_w, filt);

    dim3 gp(NN / 2, CCH);
    proj_kernel<<<gp, 256, 0, stream>>>(X, Ws, Xp);

    // CSR build
    const int eblocks = (NTOT + 255) / 256;
    count_kernel<<<eblocks, 256, 0, stream>>>(edge_index, cnt);
    scan1_kernel<<<P_BLOCKS, 256, 0, stream>>>(cnt, part);
    scan2_kernel<<<1, 256, 0, stream>>>(part);
    scan3_kernel<<<P_BLOCKS, 256, 0, stream>>>(cnt, part, base);
    fill_kernel<<<eblocks, 256, 0, stream>>>(edge_index, edge_value, base, cur, scol, sval);

    // propagation (gather, no atomics, no memset of H)
    const int gblocks = (NN * CCH + 3) / 4;
    gather_kernel<<<gblocks, 256, 0, stream>>>(Xp, A, base, cnt, scol, sval, filt);
    gather_kernel<<<gblocks, 256, 0, stream>>>(A, B, base, cnt, scol, sval, filt + CCH * ETY);

    lin_kernel<<<NN / 2, 256, 0, stream>>>(Xp, B, lin1_w, lin1_b, lin2_w, lin2_b, out);
}

// Round 3
// 1555.446 us; speedup vs baseline: 6.0624x; 1.6527x over previous
//
#include <hip/hip_runtime.h>

#define NN   100000   // num_nodes
#define ETY  5        // edge types
#define NE   500000   // edges per type
#define WIN  256
#define WOUT 128
#define CCH  2
#define LAY  2
#define NCLS 3

#define M_BUCKETS (ETY * NN)          // 500000 (j,row) buckets
#define NTOT      (ETY * NE)          // 2500000 edges total
#define SCAN_CHUNK 1024
#define P_BLOCKS  ((M_BUCKETS + SCAN_CHUNK - 1) / SCAN_CHUNK)   // 489

typedef __attribute__((ext_vector_type(8))) short bf16x8;
typedef __attribute__((ext_vector_type(4))) float f32x4;

__device__ __forceinline__ unsigned short f2bf(float f) {
    union { float f; unsigned u; } v; v.f = f;
    unsigned u = v.u + 0x7FFFu + ((v.u >> 16) & 1u);
    return (unsigned short)(u >> 16);
}

__device__ __forceinline__ bf16x8 pack8(float4 a, float4 b) {
    bf16x8 r;
    r[0] = (short)f2bf(a.x); r[1] = (short)f2bf(a.y);
    r[2] = (short)f2bf(a.z); r[3] = (short)f2bf(a.w);
    r[4] = (short)f2bf(b.x); r[5] = (short)f2bf(b.y);
    r[6] = (short)f2bf(b.z); r[7] = (short)f2bf(b.w);
    return r;
}

// ---------------- softmax over edge types for each (layer, channel) ----------------
__global__ void filt_kernel(const float* __restrict__ conv_w, float* __restrict__ filt) {
    int g = threadIdx.x;
    if (g < LAY * CCH) {
        float m = -1e30f;
        for (int j = 0; j < ETY; ++j) m = fmaxf(m, conv_w[g * ETY + j]);
        float e[ETY], s = 0.f;
        for (int j = 0; j < ETY; ++j) { e[j] = __expf(conv_w[g * ETY + j] - m); s += e[j]; }
        float inv = 1.f / s;
        for (int j = 0; j < ETY; ++j) filt[g * ETY + j] = e[j] * inv;
    }
}

// ---------------- weight conversion: Ws [C][K][N] -> Wsb [C][N][K] bf16; w1 [K2][N] -> w1b [N][K2] ----------------
__global__ void wconv_kernel(const float* __restrict__ Ws, const float* __restrict__ w1,
                             unsigned short* __restrict__ Wsb, unsigned short* __restrict__ w1b) {
    int i = blockIdx.x * 256 + threadIdx.x;
    if (i < CCH * WOUT * WIN) {                    // 65536
        int c = i / (WOUT * WIN);
        int r = i - c * WOUT * WIN;
        int n = r / WIN;
        int k = r - n * WIN;
        Wsb[i] = f2bf(Ws[((size_t)c * WIN + k) * WOUT + n]);
    }
    if (i < WOUT * (CCH * WOUT)) {                 // 32768: [128][256]
        int n = i / (CCH * WOUT);
        int k = i - n * (CCH * WOUT);
        w1b[i] = f2bf(w1[(size_t)k * WOUT + n]);
    }
}

// ---------------- X_[c] = X @ Ws[c] via bf16 MFMA: 4 waves, 64 rows x 128 cols per block ----------------
__global__ void proj_kernel(const float* __restrict__ X, const unsigned short* __restrict__ Wsb,
                            float* __restrict__ Xp) {
    const int tid  = threadIdx.x;
    const int lane = tid & 63;
    const int wv   = tid >> 6;
    const int c    = blockIdx.y;
    const int row0 = blockIdx.x * 64 + wv * 16;
    const int ar   = lane & 15;
    const int kg   = lane >> 4;
    int arow = row0 + ar; if (arow >= NN) arow = NN - 1;
    const float* xrow = X + (size_t)arow * WIN + kg * 8;
    const unsigned short* Bb = Wsb + (size_t)c * WOUT * WIN;   // [128][256] bf16

    f32x4 acc[8];
#pragma unroll
    for (int nt = 0; nt < 8; ++nt) acc[nt] = (f32x4){0.f, 0.f, 0.f, 0.f};

#pragma unroll
    for (int kk = 0; kk < 8; ++kk) {
        float4 a0 = *(const float4*)(xrow + kk * 32);
        float4 a1 = *(const float4*)(xrow + kk * 32 + 4);
        bf16x8 af = pack8(a0, a1);
#pragma unroll
        for (int nt = 0; nt < 8; ++nt) {
            const bf16x8 bfm = *(const bf16x8*)(Bb + (size_t)(nt * 16 + ar) * WIN + kk * 32 + kg * 8);
            acc[nt] = __builtin_amdgcn_mfma_f32_16x16x32_bf16(af, bfm, acc[nt], 0, 0, 0);
        }
    }
    float* outp = Xp + (size_t)c * NN * WOUT;
#pragma unroll
    for (int nt = 0; nt < 8; ++nt) {
#pragma unroll
        for (int q = 0; q < 4; ++q) {
            int r = row0 + kg * 4 + q;
            if (r < NN) outp[(size_t)r * WOUT + nt * 16 + ar] = acc[nt][q];
        }
    }
}

// ---------------- CSR build ----------------
__global__ void count_kernel(const int* __restrict__ edge_index, int* __restrict__ cnt) {
    int i = blockIdx.x * 256 + threadIdx.x;
    if (i >= NTOT) return;
    int j = i / NE;
    int e = i - j * NE;
    int row = edge_index[(size_t)j * 2 * NE + e];
    atomicAdd(&cnt[j * NN + row], 1);
}

__global__ void scan1_kernel(const int* __restrict__ cnt, int* __restrict__ part) {
    __shared__ int sm[256];
    int b = blockIdx.x, t = threadIdx.x;
    int i0 = b * SCAN_CHUNK;
    int s = 0;
    for (int k = t; k < SCAN_CHUNK; k += 256) {
        int i = i0 + k;
        if (i < M_BUCKETS) s += cnt[i];
    }
    sm[t] = s;
    __syncthreads();
    for (int off = 128; off > 0; off >>= 1) {
        if (t < off) sm[t] += sm[t + off];
        __syncthreads();
    }
    if (t == 0) part[b] = sm[0];
}

__global__ void scan2_kernel(int* __restrict__ part) {
    __shared__ int sm[512];
    int t = threadIdx.x;
    for (int k = t; k < P_BLOCKS; k += 256) sm[k] = part[k];
    __syncthreads();
    if (t == 0) {
        int run = 0;
        for (int p = 0; p < P_BLOCKS; ++p) { int v = sm[p]; sm[p] = run; run += v; }
    }
    __syncthreads();
    for (int k = t; k < P_BLOCKS; k += 256) part[k] = sm[k];
}

__global__ void scan3_kernel(const int* __restrict__ cnt, const int* __restrict__ part,
                             int* __restrict__ base) {
    __shared__ int wsum[4];
    int b = blockIdx.x, t = threadIdx.x;
    int i0 = b * SCAN_CHUNK + t * 4;
    int v0 = (i0 + 0 < M_BUCKETS) ? cnt[i0 + 0] : 0;
    int v1 = (i0 + 1 < M_BUCKETS) ? cnt[i0 + 1] : 0;
    int v2 = (i0 + 2 < M_BUCKETS) ? cnt[i0 + 2] : 0;
    int v3 = (i0 + 3 < M_BUCKETS) ? cnt[i0 + 3] : 0;
    int s = v0 + v1 + v2 + v3;
    int lane = t & 63;
    int x = s;
    for (int off = 1; off < 64; off <<= 1) {
        int y = __shfl_up(x, off);
        if (lane >= off) x += y;
    }
    if (lane == 63) wsum[t >> 6] = x;
    __syncthreads();
    int wb = 0;
    for (int k = 0; k < (t >> 6); ++k) wb += wsum[k];
    int excl = wb + x - s + part[b];
    if (i0 + 0 < M_BUCKETS) base[i0 + 0] = excl;
    if (i0 + 1 < M_BUCKETS) base[i0 + 1] = excl + v0;
    if (i0 + 2 < M_BUCKETS) base[i0 + 2] = excl + v0 + v1;
    if (i0 + 3 < M_BUCKETS) base[i0 + 3] = excl + v0 + v1 + v2;
}

__global__ void fill_kernel(const int* __restrict__ edge_index, const float* __restrict__ edge_value,
                            const int* __restrict__ base, int* __restrict__ cur,
                            int* __restrict__ scol, float* __restrict__ sval) {
    int i = blockIdx.x * 256 + threadIdx.x;
    if (i >= NTOT) return;
    int j = i / NE;
    int e = i - j * NE;
    int row = edge_index[(size_t)j * 2 * NE + e];
    int col = edge_index[(size_t)j * 2 * NE + NE + e];
    int idx = j * NN + row;
    int pos = base[idx] + atomicAdd(&cur[idx], 1);
    scol[pos] = col;
    sval[pos] = edge_value[(size_t)j * NE + e];
}

// ---------------- gather propagation: one wave per (node, channel) ----------------
__global__ void gather_kernel(const float* __restrict__ Hin, float* __restrict__ Hnew,
                              const int* __restrict__ base, const int* __restrict__ cnt,
                              const int* __restrict__ scol, const float* __restrict__ sval,
                              const float* __restrict__ filt) {
    const int lane = threadIdx.x & 63;
    const int wib  = threadIdx.x >> 6;
    const int u = blockIdx.x * 4 + wib;
    if (u >= NN * CCH) return;
    const int c = u & 1;
    const int n = u >> 1;
    const float* Hc = Hin + (size_t)c * NN * WOUT;
    float ax = 0.f, ay = 0.f;
    for (int j = 0; j < ETY; ++j) {
        const float wj = filt[c * ETY + j];
        const int idx = j * NN + n;
        const int s = base[idx];
        const int e = s + cnt[idx];
        for (int k = s; k < e; ++k) {
            const int col = scol[k];
            const float w = wj * sval[k];
            const float2 v = ((const float2*)(Hc + (size_t)col * WOUT))[lane];
            ax = fmaf(w, v.x, ax);
            ay = fmaf(w, v.y, ay);
        }
    }
    float2 r; r.x = ax; r.y = ay;
    ((float2*)(Hnew + ((size_t)c * NN + n) * WOUT))[lane] = r;
}

// ---------------- fused lin1+lin2 via bf16 MFMA: 64 rows per block ----------------
__global__ void lin_kernel(const float* __restrict__ Xp, const float* __restrict__ Hf,
                           const unsigned short* __restrict__ w1b, const float* __restrict__ b1,
                           const float* __restrict__ w2, const float* __restrict__ b2,
                           float* __restrict__ out) {
    const int tid  = threadIdx.x;
    const int lane = tid & 63;
    const int wv   = tid >> 6;
    const int row0 = blockIdx.x * 64 + wv * 16;
    const int ar   = lane & 15;
    const int kg   = lane >> 4;
    int arow = row0 + ar; if (arow >= NN) arow = NN - 1;

    f32x4 acc[8];
#pragma unroll
    for (int nt = 0; nt < 8; ++nt) acc[nt] = (f32x4){0.f, 0.f, 0.f, 0.f};

#pragma unroll
    for (int kk = 0; kk < 8; ++kk) {
        const int k0 = kk * 32 + kg * 8;           // concat feature index, 8-chunk
        const int c  = k0 >> 7;
        const int d  = k0 & 127;
        const float* xp = Xp + ((size_t)c * NN + arow) * WOUT + d;
        const float* hp = Hf + ((size_t)c * NN + arow) * WOUT + d;
        float4 x0 = *(const float4*)(xp);
        float4 x1 = *(const float4*)(xp + 4);
        float4 h0 = *(const float4*)(hp);
        float4 h1 = *(const float4*)(hp + 4);
        float4 v0, v1;
        v0.x = fmaxf(0.1f * x0.x + 0.9f * h0.x, 0.f);
        v0.y = fmaxf(0.1f * x0.y + 0.9f * h0.y, 0.f);
        v0.z = fmaxf(0.1f * x0.z + 0.9f * h0.z, 0.f);
        v0.w = fmaxf(0.1f * x0.w + 0.9f * h0.w, 0.f);
        v1.x = fmaxf(0.1f * x1.x + 0.9f * h1.x, 0.f);
        v1.y = fmaxf(0.1f * x1.y + 0.9f * h1.y, 0.f);
        v1.z = fmaxf(0.1f * x1.z + 0.9f * h1.z, 0.f);
        v1.w = fmaxf(0.1f * x1.w + 0.9f * h1.w, 0.f);
        bf16x8 af = pack8(v0, v1);
#pragma unroll
        for (int nt = 0; nt < 8; ++nt) {
            const bf16x8 bfm = *(const bf16x8*)(w1b + (size_t)(nt * 16 + ar) * (CCH * WOUT) + k0);
            acc[nt] = __builtin_amdgcn_mfma_f32_16x16x32_bf16(af, bfm, acc[nt], 0, 0, 0);
        }
    }

    // epilogue: h1[row][col] = acc + b1[col]; out[row][m] = sum_col h1*w2[col][m] + b2[m]
    float b1v[8], w2v[8][NCLS];
#pragma unroll
    for (int nt = 0; nt < 8; ++nt) {
        int col = nt * 16 + ar;
        b1v[nt] = b1[col];
#pragma unroll
        for (int m = 0; m < NCLS; ++m) w2v[nt][m] = w2[col * NCLS + m];
    }
#pragma unroll
    for (int q = 0; q < 4; ++q) {
        float pm[NCLS] = {0.f, 0.f, 0.f};
#pragma unroll
        for (int nt = 0; nt < 8; ++nt) {
            float h = acc[nt][q] + b1v[nt];
#pragma unroll
            for (int m = 0; m < NCLS; ++m) pm[m] = fmaf(h, w2v[nt][m], pm[m]);
        }
#pragma unroll
        for (int m = 0; m < NCLS; ++m) {
            pm[m] += __shfl_xor(pm[m], 1);
            pm[m] += __shfl_xor(pm[m], 2);
            pm[m] += __shfl_xor(pm[m], 4);
            pm[m] += __shfl_xor(pm[m], 8);
        }
        int r = row0 + kg * 4 + q;
        if (ar == 0 && r < NN) {
            out[(size_t)r * NCLS + 0] = pm[0] + b2[0];
            out[(size_t)r * NCLS + 1] = pm[1] + b2[1];
            out[(size_t)r * NCLS + 2] = pm[2] + b2[2];
        }
    }
}

extern "C" void kernel_launch(void* const* d_in, const int* in_sizes, int n_in,
                              void* d_out, int out_size, void* d_ws, size_t ws_size,
                              hipStream_t stream) {
    const int*   edge_index = (const int*)d_in[0];
    const float* edge_value = (const float*)d_in[1];
    const float* X          = (const float*)d_in[2];
    const float* Ws         = (const float*)d_in[3];
    const float* conv_w     = (const float*)d_in[4];
    const float* lin1_w     = (const float*)d_in[5];
    const float* lin1_b     = (const float*)d_in[6];
    const float* lin2_w     = (const float*)d_in[7];
    const float* lin2_b     = (const float*)d_in[8];
    float* out = (float*)d_out;

    float* ws = (float*)d_ws;
    const size_t CN = (size_t)CCH * NN * WOUT;
    float* Xp   = ws;
    float* A    = Xp + CN;
    float* B    = A + CN;
    float* filt = B + CN;
    int*   cnt  = (int*)(filt + 32);
    int*   base = cnt + M_BUCKETS;
    int*   cur  = base + M_BUCKETS;
    int*   part = cur + M_BUCKETS;
    int*   scol = part + 512;
    float* sval = (float*)(scol + NTOT);
    unsigned short* Wsb = (unsigned short*)(sval + NTOT);          // [C][128][256] bf16
    unsigned short* w1b = Wsb + (size_t)CCH * WOUT * WIN;          // [128][256] bf16

    hipMemsetAsync(cnt, 0, M_BUCKETS * sizeof(int), stream);
    hipMemsetAsync(cur, 0, M_BUCKETS * sizeof(int), stream);

    filt_kernel<<<1, 64, 0, stream>>>(conv_w, filt);
    wconv_kernel<<<(CCH * WOUT * WIN + 255) / 256, 256, 0, stream>>>(Ws, lin1_w, Wsb, w1b);

    dim3 gp((NN + 63) / 64, CCH);
    proj_kernel<<<gp, 256, 0, stream>>>(X, Wsb, Xp);

    const int eblocks = (NTOT + 255) / 256;
    count_kernel<<<eblocks, 256, 0, stream>>>(edge_index, cnt);
    scan1_kernel<<<P_BLOCKS, 256, 0, stream>>>(cnt, part);
    scan2_kernel<<<1, 256, 0, stream>>>(part);
    scan3_kernel<<<P_BLOCKS, 256, 0, stream>>>(cnt, part, base);
    fill_kernel<<<eblocks, 256, 0, stream>>>(edge_index, edge_value, base, cur, scol, sval);

    const int gblocks = (NN * CCH + 3) / 4;
    gather_kernel<<<gblocks, 256, 0, stream>>>(Xp, A, base, cnt, scol, sval, filt);
    gather_kernel<<<gblocks, 256, 0, stream>>>(A, B, base, cnt, scol, sval, filt + CCH * ETY);

    lin_kernel<<<(NN + 63) / 64, 256, 0, stream>>>(Xp, B, w1b, lin1_b, lin2_w, lin2_b, out);
}

// Round 4
// 1060.607 us; speedup vs baseline: 8.8909x; 1.4666x over previous
//
#include <hip/hip_runtime.h>

#define NN   100000   // num_nodes
#define ETY  5        // edge types
#define NE   500000   // edges per type
#define WIN  256
#define WOUT 128
#define CCH  2
#define LAY  2
#define NCLS 3

#define M_BUCKETS (ETY * NN)          // 500000 (j,row) buckets
#define NTOT      (ETY * NE)          // 2500000 edges total
#define SCAN_CHUNK 1024
#define P_BLOCKS  ((M_BUCKETS + SCAN_CHUNK - 1) / SCAN_CHUNK)   // 489

typedef __attribute__((ext_vector_type(8))) short bf16x8;
typedef __attribute__((ext_vector_type(4))) float f32x4;

__device__ __forceinline__ unsigned short f2bf(float f) {
    union { float f; unsigned u; } v; v.f = f;
    unsigned u = v.u + 0x7FFFu + ((v.u >> 16) & 1u);
    return (unsigned short)(u >> 16);
}
__device__ __forceinline__ float bf2f(unsigned short u) {
    union { unsigned u; float f; } v; v.u = ((unsigned)u) << 16;
    return v.f;
}

__device__ __forceinline__ bf16x8 pack8(float4 a, float4 b) {
    bf16x8 r;
    r[0] = (short)f2bf(a.x); r[1] = (short)f2bf(a.y);
    r[2] = (short)f2bf(a.z); r[3] = (short)f2bf(a.w);
    r[4] = (short)f2bf(b.x); r[5] = (short)f2bf(b.y);
    r[6] = (short)f2bf(b.z); r[7] = (short)f2bf(b.w);
    return r;
}

// ---------------- softmax over edge types for each (layer, channel) ----------------
__global__ void filt_kernel(const float* __restrict__ conv_w, float* __restrict__ filt) {
    int g = threadIdx.x;
    if (g < LAY * CCH) {
        float m = -1e30f;
        for (int j = 0; j < ETY; ++j) m = fmaxf(m, conv_w[g * ETY + j]);
        float e[ETY], s = 0.f;
        for (int j = 0; j < ETY; ++j) { e[j] = __expf(conv_w[g * ETY + j] - m); s += e[j]; }
        float inv = 1.f / s;
        for (int j = 0; j < ETY; ++j) filt[g * ETY + j] = e[j] * inv;
    }
}

// ---------------- weight conversion: Ws [C][K][N] -> Wsb [C][N][K] bf16; w1 [K2][N] -> w1b [N][K2] ----------------
__global__ void wconv_kernel(const float* __restrict__ Ws, const float* __restrict__ w1,
                             unsigned short* __restrict__ Wsb, unsigned short* __restrict__ w1b) {
    int i = blockIdx.x * 256 + threadIdx.x;
    if (i < CCH * WOUT * WIN) {                    // 65536
        int c = i / (WOUT * WIN);
        int r = i - c * WOUT * WIN;
        int n = r / WIN;
        int k = r - n * WIN;
        Wsb[i] = f2bf(Ws[((size_t)c * WIN + k) * WOUT + n]);
    }
    if (i < WOUT * (CCH * WOUT)) {                 // 32768: [128][256]
        int n = i / (CCH * WOUT);
        int k = i - n * (CCH * WOUT);
        w1b[i] = f2bf(w1[(size_t)k * WOUT + n]);
    }
}

// ---------------- Xpb[n][d][c] = (X @ Ws[c])[n][d] in bf16, both channels per block ----------------
__global__ void proj_kernel(const float* __restrict__ X, const unsigned short* __restrict__ Wsb,
                            unsigned short* __restrict__ Xpb) {
    const int tid  = threadIdx.x;
    const int lane = tid & 63;
    const int wv   = tid >> 6;
    const int row0 = blockIdx.x * 64 + wv * 16;
    const int ar   = lane & 15;
    const int kg   = lane >> 4;
    int arow = row0 + ar; if (arow >= NN) arow = NN - 1;
    const float* xrow = X + (size_t)arow * WIN + kg * 8;

    f32x4 acc[2][8];
#pragma unroll
    for (int c = 0; c < 2; ++c)
#pragma unroll
        for (int nt = 0; nt < 8; ++nt) acc[c][nt] = (f32x4){0.f, 0.f, 0.f, 0.f};

#pragma unroll
    for (int kk = 0; kk < 8; ++kk) {
        float4 a0 = *(const float4*)(xrow + kk * 32);
        float4 a1 = *(const float4*)(xrow + kk * 32 + 4);
        bf16x8 af = pack8(a0, a1);
#pragma unroll
        for (int c = 0; c < 2; ++c)
#pragma unroll
            for (int nt = 0; nt < 8; ++nt) {
                const bf16x8 bfm = *(const bf16x8*)(Wsb + (size_t)c * WOUT * WIN +
                                                    (size_t)(nt * 16 + ar) * WIN + kk * 32 + kg * 8);
                acc[c][nt] = __builtin_amdgcn_mfma_f32_16x16x32_bf16(af, bfm, acc[c][nt], 0, 0, 0);
            }
    }
#pragma unroll
    for (int nt = 0; nt < 8; ++nt) {
#pragma unroll
        for (int q = 0; q < 4; ++q) {
            int r = row0 + kg * 4 + q;
            if (r < NN) {
                int col = nt * 16 + ar;
                ushort2 w;
                w.x = f2bf(acc[0][nt][q]);
                w.y = f2bf(acc[1][nt][q]);
                *(ushort2*)(Xpb + (size_t)r * (WOUT * CCH) + col * 2) = w;
            }
        }
    }
}

// ---------------- CSR build ----------------
__global__ void count_kernel(const int* __restrict__ edge_index, int* __restrict__ cnt) {
    int i = blockIdx.x * 256 + threadIdx.x;
    if (i >= NTOT) return;
    int j = i / NE;
    int e = i - j * NE;
    int row = edge_index[(size_t)j * 2 * NE + e];
    atomicAdd(&cnt[j * NN + row], 1);
}

__global__ void scan1_kernel(const int* __restrict__ cnt, int* __restrict__ part) {
    __shared__ int sm[256];
    int b = blockIdx.x, t = threadIdx.x;
    int i0 = b * SCAN_CHUNK;
    int s = 0;
    for (int k = t; k < SCAN_CHUNK; k += 256) {
        int i = i0 + k;
        if (i < M_BUCKETS) s += cnt[i];
    }
    sm[t] = s;
    __syncthreads();
    for (int off = 128; off > 0; off >>= 1) {
        if (t < off) sm[t] += sm[t + off];
        __syncthreads();
    }
    if (t == 0) part[b] = sm[0];
}

__global__ void scan2_kernel(int* __restrict__ part) {
    __shared__ int sm[512];
    int t = threadIdx.x;
    for (int k = t; k < P_BLOCKS; k += 256) sm[k] = part[k];
    __syncthreads();
    if (t == 0) {
        int run = 0;
        for (int p = 0; p < P_BLOCKS; ++p) { int v = sm[p]; sm[p] = run; run += v; }
    }
    __syncthreads();
    for (int k = t; k < P_BLOCKS; k += 256) part[k] = sm[k];
}

__global__ void scan3_kernel(const int* __restrict__ cnt, const int* __restrict__ part,
                             int* __restrict__ base) {
    __shared__ int wsum[4];
    int b = blockIdx.x, t = threadIdx.x;
    int i0 = b * SCAN_CHUNK + t * 4;
    int v0 = (i0 + 0 < M_BUCKETS) ? cnt[i0 + 0] : 0;
    int v1 = (i0 + 1 < M_BUCKETS) ? cnt[i0 + 1] : 0;
    int v2 = (i0 + 2 < M_BUCKETS) ? cnt[i0 + 2] : 0;
    int v3 = (i0 + 3 < M_BUCKETS) ? cnt[i0 + 3] : 0;
    int s = v0 + v1 + v2 + v3;
    int lane = t & 63;
    int x = s;
    for (int off = 1; off < 64; off <<= 1) {
        int y = __shfl_up(x, off);
        if (lane >= off) x += y;
    }
    if (lane == 63) wsum[t >> 6] = x;
    __syncthreads();
    int wb = 0;
    for (int k = 0; k < (t >> 6); ++k) wb += wsum[k];
    int excl = wb + x - s + part[b];
    if (i0 + 0 < M_BUCKETS) base[i0 + 0] = excl;
    if (i0 + 1 < M_BUCKETS) base[i0 + 1] = excl + v0;
    if (i0 + 2 < M_BUCKETS) base[i0 + 2] = excl + v0 + v1;
    if (i0 + 3 < M_BUCKETS) base[i0 + 3] = excl + v0 + v1 + v2;
}

__global__ void fill_kernel(const int* __restrict__ edge_index, const float* __restrict__ edge_value,
                            const int* __restrict__ base, int* __restrict__ cur,
                            int* __restrict__ scol, float* __restrict__ sval) {
    int i = blockIdx.x * 256 + threadIdx.x;
    if (i >= NTOT) return;
    int j = i / NE;
    int e = i - j * NE;
    int row = edge_index[(size_t)j * 2 * NE + e];
    int col = edge_index[(size_t)j * 2 * NE + NE + e];
    int idx = j * NN + row;
    int pos = base[idx] + atomicAdd(&cur[idx], 1);
    scol[pos] = col;
    sval[pos] = edge_value[(size_t)j * NE + e];
}

// ---------------- gather propagation: one wave per node, BOTH channels ----------------
// H layout [n][d][c] bf16: lane handles feats {2*lane, 2*lane+1} x {c0,c1} = one ushort4 (8B)
__global__ void gather_kernel(const unsigned short* __restrict__ Hin, unsigned short* __restrict__ Hnew,
                              const int* __restrict__ base, const int* __restrict__ cnt,
                              const int* __restrict__ scol, const float* __restrict__ sval,
                              const float* __restrict__ filt /* [C][ETY] this layer */) {
    const int lane = threadIdx.x & 63;
    const int wib  = threadIdx.x >> 6;
    const int n = blockIdx.x * 4 + wib;
    if (n >= NN) return;
    const unsigned short* hp = Hin + lane * 4;
    float a0 = 0.f, a1 = 0.f, a2 = 0.f, a3 = 0.f;
#pragma unroll
    for (int j = 0; j < ETY; ++j) {
        const float f0 = filt[j];
        const float f1 = filt[ETY + j];
        const int idx = j * NN + n;
        const int s = base[idx];
        const int e = s + cnt[idx];
        for (int k = s; k < e; ++k) {
            const int col = scol[k];
            const float w = sval[k];
            const ushort4 v = *(const ushort4*)(hp + (size_t)col * (WOUT * CCH));
            const float w0 = f0 * w, w1 = f1 * w;
            a0 = fmaf(w0, bf2f(v.x), a0);
            a1 = fmaf(w1, bf2f(v.y), a1);
            a2 = fmaf(w0, bf2f(v.z), a2);
            a3 = fmaf(w1, bf2f(v.w), a3);
        }
    }
    ushort4 r4;
    r4.x = f2bf(a0); r4.y = f2bf(a1); r4.z = f2bf(a2); r4.w = f2bf(a3);
    *(ushort4*)(Hnew + (size_t)n * (WOUT * CCH) + lane * 4) = r4;
}

// ---------------- fused lin1+lin2 via bf16 MFMA, interleaved bf16 inputs ----------------
__global__ void lin_kernel(const unsigned short* __restrict__ Xpb, const unsigned short* __restrict__ Hb,
                           const unsigned short* __restrict__ w1b, const float* __restrict__ b1,
                           const float* __restrict__ w2, const float* __restrict__ b2,
                           float* __restrict__ out) {
    const int tid  = threadIdx.x;
    const int lane = tid & 63;
    const int wv   = tid >> 6;
    const int row0 = blockIdx.x * 64 + wv * 16;
    const int ar   = lane & 15;
    const int kg   = lane >> 4;
    int arow = row0 + ar; if (arow >= NN) arow = NN - 1;
    const unsigned short* xr = Xpb + (size_t)arow * (WOUT * CCH);
    const unsigned short* hr = Hb  + (size_t)arow * (WOUT * CCH);

    f32x4 acc[8];
#pragma unroll
    for (int nt = 0; nt < 8; ++nt) acc[nt] = (f32x4){0.f, 0.f, 0.f, 0.f};

    bf16x8 af1s[4];                    // stashed c=1 fragments for kk=4..7
#pragma unroll
    for (int kk = 0; kk < 4; ++kk) {
        const int d = kk * 32 + kg * 8;          // feature block (channel-agnostic)
        bf16x8 af0, af1;
#pragma unroll
        for (int t = 0; t < 4; ++t) {
            ushort4 xu = *(const ushort4*)(xr + 2 * d + 4 * t);
            ushort4 hu = *(const ushort4*)(hr + 2 * d + 4 * t);
            float v00 = fmaxf(0.1f * bf2f(xu.x) + 0.9f * bf2f(hu.x), 0.f);  // feat d+2t,   c0
            float v01 = fmaxf(0.1f * bf2f(xu.y) + 0.9f * bf2f(hu.y), 0.f);  // feat d+2t,   c1
            float v10 = fmaxf(0.1f * bf2f(xu.z) + 0.9f * bf2f(hu.z), 0.f);  // feat d+2t+1, c0
            float v11 = fmaxf(0.1f * bf2f(xu.w) + 0.9f * bf2f(hu.w), 0.f);  // feat d+2t+1, c1
            af0[2 * t]     = (short)f2bf(v00);
            af0[2 * t + 1] = (short)f2bf(v10);
            af1[2 * t]     = (short)f2bf(v01);
            af1[2 * t + 1] = (short)f2bf(v11);
        }
        af1s[kk] = af1;
        const int k0 = kk * 32 + kg * 8;         // concat-k for c=0 pass
#pragma unroll
        for (int nt = 0; nt < 8; ++nt) {
            const bf16x8 bfm = *(const bf16x8*)(w1b + (size_t)(nt * 16 + ar) * (CCH * WOUT) + k0);
            acc[nt] = __builtin_amdgcn_mfma_f32_16x16x32_bf16(af0, bfm, acc[nt], 0, 0, 0);
        }
    }
#pragma unroll
    for (int kk = 4; kk < 8; ++kk) {
        const int k0 = kk * 32 + kg * 8;         // concat-k for c=1 pass
        const bf16x8 af = af1s[kk - 4];
#pragma unroll
        for (int nt = 0; nt < 8; ++nt) {
            const bf16x8 bfm = *(const bf16x8*)(w1b + (size_t)(nt * 16 + ar) * (CCH * WOUT) + k0);
            acc[nt] = __builtin_amdgcn_mfma_f32_16x16x32_bf16(af, bfm, acc[nt], 0, 0, 0);
        }
    }

    // epilogue: h1 = acc + b1; out = h1 @ w2 + b2 (reduce over 16 ar lanes)
    float b1v[8], w2v[8][NCLS];
#pragma unroll
    for (int nt = 0; nt < 8; ++nt) {
        int col = nt * 16 + ar;
        b1v[nt] = b1[col];
#pragma unroll
        for (int m = 0; m < NCLS; ++m) w2v[nt][m] = w2[col * NCLS + m];
    }
#pragma unroll
    for (int q = 0; q < 4; ++q) {
        float pm[NCLS] = {0.f, 0.f, 0.f};
#pragma unroll
        for (int nt = 0; nt < 8; ++nt) {
            float h = acc[nt][q] + b1v[nt];
#pragma unroll
            for (int m = 0; m < NCLS; ++m) pm[m] = fmaf(h, w2v[nt][m], pm[m]);
        }
#pragma unroll
        for (int m = 0; m < NCLS; ++m) {
            pm[m] += __shfl_xor(pm[m], 1);
            pm[m] += __shfl_xor(pm[m], 2);
            pm[m] += __shfl_xor(pm[m], 4);
            pm[m] += __shfl_xor(pm[m], 8);
        }
        int r = row0 + kg * 4 + q;
        if (ar == 0 && r < NN) {
            out[(size_t)r * NCLS + 0] = pm[0] + b2[0];
            out[(size_t)r * NCLS + 1] = pm[1] + b2[1];
            out[(size_t)r * NCLS + 2] = pm[2] + b2[2];
        }
    }
}

extern "C" void kernel_launch(void* const* d_in, const int* in_sizes, int n_in,
                              void* d_out, int out_size, void* d_ws, size_t ws_size,
                              hipStream_t stream) {
    const int*   edge_index = (const int*)d_in[0];
    const float* edge_value = (const float*)d_in[1];
    const float* X          = (const float*)d_in[2];
    const float* Ws         = (const float*)d_in[3];
    const float* conv_w     = (const float*)d_in[4];
    const float* lin1_w     = (const float*)d_in[5];
    const float* lin1_b     = (const float*)d_in[6];
    const float* lin2_w     = (const float*)d_in[7];
    const float* lin2_b     = (const float*)d_in[8];
    float* out = (float*)d_out;

    const size_t CNU = (size_t)NN * WOUT * CCH;          // 25.6M ushorts per H buffer
    unsigned short* Xpb = (unsigned short*)d_ws;          // [N][128][2] bf16
    unsigned short* Ab  = Xpb + CNU;
    unsigned short* Bb  = Ab + CNU;
    float* filt = (float*)(Bb + CNU);                     // [L][C][ETY] (pad to 32 floats)
    int*   cnt  = (int*)(filt + 32);                      // [M_BUCKETS]
    int*   base = cnt + M_BUCKETS;
    int*   cur  = base + M_BUCKETS;
    int*   part = cur + M_BUCKETS;                        // [512]
    int*   scol = part + 512;                             // [NTOT]
    float* sval = (float*)(scol + NTOT);                  // [NTOT]
    unsigned short* Wsb = (unsigned short*)(sval + NTOT); // [C][128][256] bf16
    unsigned short* w1b = Wsb + (size_t)CCH * WOUT * WIN; // [128][256] bf16

    hipMemsetAsync(cnt, 0, M_BUCKETS * sizeof(int), stream);
    hipMemsetAsync(cur, 0, M_BUCKETS * sizeof(int), stream);

    filt_kernel<<<1, 64, 0, stream>>>(conv_w, filt);
    wconv_kernel<<<(CCH * WOUT * WIN + 255) / 256, 256, 0, stream>>>(Ws, lin1_w, Wsb, w1b);

    proj_kernel<<<(NN + 63) / 64, 256, 0, stream>>>(X, Wsb, Xpb);

    const int eblocks = (NTOT + 255) / 256;
    count_kernel<<<eblocks, 256, 0, stream>>>(edge_index, cnt);
    scan1_kernel<<<P_BLOCKS, 256, 0, stream>>>(cnt, part);
    scan2_kernel<<<1, 256, 0, stream>>>(part);
    scan3_kernel<<<P_BLOCKS, 256, 0, stream>>>(cnt, part, base);
    fill_kernel<<<eblocks, 256, 0, stream>>>(edge_index, edge_value, base, cur, scol, sval);

    const int gblocks = (NN + 3) / 4;
    gather_kernel<<<gblocks, 256, 0, stream>>>(Xpb, Ab, base, cnt, scol, sval, filt);
    gather_kernel<<<gblocks, 256, 0, stream>>>(Ab, Bb, base, cnt, scol, sval, filt + CCH * ETY);

    lin_kernel<<<(NN + 63) / 64, 256, 0, stream>>>(Xpb, Bb, w1b, lin1_b, lin2_w, lin2_b, out);
}

// Round 5
// 851.881 us; speedup vs baseline: 11.0693x; 1.2450x over previous
//
#include <hip/hip_runtime.h>

#define NN   100000   // num_nodes
#define ETY  5        // edge types
#define NE   500000   // edges per type
#define WIN  256
#define WOUT 128
#define CCH  2
#define LAY  2
#define NCLS 3

#define NTOT      (ETY * NE)          // 2500000 edges total
#define SCAN_CHUNK 1024
#define P_BLOCKS  ((NN + SCAN_CHUNK - 1) / SCAN_CHUNK)   // 98 (buckets = nodes now)
#define COLMASK   0x1FFFF             // NN < 131072

typedef __attribute__((ext_vector_type(8))) short bf16x8;
typedef __attribute__((ext_vector_type(4))) float f32x4;

__device__ __forceinline__ unsigned short f2bf(float f) {
    union { float f; unsigned u; } v; v.f = f;
    unsigned u = v.u + 0x7FFFu + ((v.u >> 16) & 1u);
    return (unsigned short)(u >> 16);
}
__device__ __forceinline__ float bf2f(unsigned short u) {
    union { unsigned u; float f; } v; v.u = ((unsigned)u) << 16;
    return v.f;
}

__device__ __forceinline__ bf16x8 pack8(float4 a, float4 b) {
    bf16x8 r;
    r[0] = (short)f2bf(a.x); r[1] = (short)f2bf(a.y);
    r[2] = (short)f2bf(a.z); r[3] = (short)f2bf(a.w);
    r[4] = (short)f2bf(b.x); r[5] = (short)f2bf(b.y);
    r[6] = (short)f2bf(b.z); r[7] = (short)f2bf(b.w);
    return r;
}

// ---------------- softmax over edge types for each (layer, channel) ----------------
__global__ void filt_kernel(const float* __restrict__ conv_w, float* __restrict__ filt) {
    int g = threadIdx.x;
    if (g < LAY * CCH) {
        float m = -1e30f;
        for (int j = 0; j < ETY; ++j) m = fmaxf(m, conv_w[g * ETY + j]);
        float e[ETY], s = 0.f;
        for (int j = 0; j < ETY; ++j) { e[j] = __expf(conv_w[g * ETY + j] - m); s += e[j]; }
        float inv = 1.f / s;
        for (int j = 0; j < ETY; ++j) filt[g * ETY + j] = e[j] * inv;
    }
}

// ---------------- weight conversion ----------------
__global__ void wconv_kernel(const float* __restrict__ Ws, const float* __restrict__ w1,
                             unsigned short* __restrict__ Wsb, unsigned short* __restrict__ w1b) {
    int i = blockIdx.x * 256 + threadIdx.x;
    if (i < CCH * WOUT * WIN) {
        int c = i / (WOUT * WIN);
        int r = i - c * WOUT * WIN;
        int n = r / WIN;
        int k = r - n * WIN;
        Wsb[i] = f2bf(Ws[((size_t)c * WIN + k) * WOUT + n]);
    }
    if (i < WOUT * (CCH * WOUT)) {
        int n = i / (CCH * WOUT);
        int k = i - n * (CCH * WOUT);
        w1b[i] = f2bf(w1[(size_t)k * WOUT + n]);
    }
}

// ---------------- Xpb[n][d][c] = (X @ Ws[c])[n][d] bf16 interleaved ----------------
__global__ void proj_kernel(const float* __restrict__ X, const unsigned short* __restrict__ Wsb,
                            unsigned short* __restrict__ Xpb) {
    const int tid  = threadIdx.x;
    const int lane = tid & 63;
    const int wv   = tid >> 6;
    const int row0 = blockIdx.x * 64 + wv * 16;
    const int ar   = lane & 15;
    const int kg   = lane >> 4;
    int arow = row0 + ar; if (arow >= NN) arow = NN - 1;
    const float* xrow = X + (size_t)arow * WIN + kg * 8;

    f32x4 acc[2][8];
#pragma unroll
    for (int c = 0; c < 2; ++c)
#pragma unroll
        for (int nt = 0; nt < 8; ++nt) acc[c][nt] = (f32x4){0.f, 0.f, 0.f, 0.f};

#pragma unroll
    for (int kk = 0; kk < 8; ++kk) {
        float4 a0 = *(const float4*)(xrow + kk * 32);
        float4 a1 = *(const float4*)(xrow + kk * 32 + 4);
        bf16x8 af = pack8(a0, a1);
#pragma unroll
        for (int c = 0; c < 2; ++c)
#pragma unroll
            for (int nt = 0; nt < 8; ++nt) {
                const bf16x8 bfm = *(const bf16x8*)(Wsb + (size_t)c * WOUT * WIN +
                                                    (size_t)(nt * 16 + ar) * WIN + kk * 32 + kg * 8);
                acc[c][nt] = __builtin_amdgcn_mfma_f32_16x16x32_bf16(af, bfm, acc[c][nt], 0, 0, 0);
            }
    }
#pragma unroll
    for (int nt = 0; nt < 8; ++nt) {
#pragma unroll
        for (int q = 0; q < 4; ++q) {
            int r = row0 + kg * 4 + q;
            if (r < NN) {
                int col = nt * 16 + ar;
                ushort2 w;
                w.x = f2bf(acc[0][nt][q]);
                w.y = f2bf(acc[1][nt][q]);
                *(ushort2*)(Xpb + (size_t)r * (WOUT * CCH) + col * 2) = w;
            }
        }
    }
}

// ---------------- CSR build (bucket = destination node, types merged) ----------------
__global__ void count_kernel(const int* __restrict__ edge_index, int* __restrict__ cnt) {
    int i = blockIdx.x * 256 + threadIdx.x;
    if (i >= NTOT) return;
    int j = i / NE;
    int e = i - j * NE;
    int row = edge_index[(size_t)j * 2 * NE + e];
    atomicAdd(&cnt[row], 1);
}

__global__ void scan1_kernel(const int* __restrict__ cnt, int* __restrict__ part) {
    __shared__ int sm[256];
    int b = blockIdx.x, t = threadIdx.x;
    int i0 = b * SCAN_CHUNK;
    int s = 0;
    for (int k = t; k < SCAN_CHUNK; k += 256) {
        int i = i0 + k;
        if (i < NN) s += cnt[i];
    }
    sm[t] = s;
    __syncthreads();
    for (int off = 128; off > 0; off >>= 1) {
        if (t < off) sm[t] += sm[t + off];
        __syncthreads();
    }
    if (t == 0) part[b] = sm[0];
}

__global__ void scan2_kernel(int* __restrict__ part) {
    __shared__ int sm[512];
    int t = threadIdx.x;
    for (int k = t; k < P_BLOCKS; k += 256) sm[k] = part[k];
    __syncthreads();
    if (t == 0) {
        int run = 0;
        for (int p = 0; p < P_BLOCKS; ++p) { int v = sm[p]; sm[p] = run; run += v; }
    }
    __syncthreads();
    for (int k = t; k < P_BLOCKS; k += 256) part[k] = sm[k];
}

__global__ void scan3_kernel(const int* __restrict__ cnt, const int* __restrict__ part,
                             int* __restrict__ base) {
    __shared__ int wsum[4];
    int b = blockIdx.x, t = threadIdx.x;
    int i0 = b * SCAN_CHUNK + t * 4;
    int v0 = (i0 + 0 < NN) ? cnt[i0 + 0] : 0;
    int v1 = (i0 + 1 < NN) ? cnt[i0 + 1] : 0;
    int v2 = (i0 + 2 < NN) ? cnt[i0 + 2] : 0;
    int v3 = (i0 + 3 < NN) ? cnt[i0 + 3] : 0;
    int s = v0 + v1 + v2 + v3;
    int lane = t & 63;
    int x = s;
    for (int off = 1; off < 64; off <<= 1) {
        int y = __shfl_up(x, off);
        if (lane >= off) x += y;
    }
    if (lane == 63) wsum[t >> 6] = x;
    __syncthreads();
    int wb = 0;
    for (int k = 0; k < (t >> 6); ++k) wb += wsum[k];
    int excl = wb + x - s + part[b];
    if (i0 + 0 < NN) base[i0 + 0] = excl;
    if (i0 + 1 < NN) base[i0 + 1] = excl + v0;
    if (i0 + 2 < NN) base[i0 + 2] = excl + v0 + v1;
    if (i0 + 3 < NN) base[i0 + 3] = excl + v0 + v1 + v2;
}

__global__ void fill_kernel(const int* __restrict__ edge_index, const float* __restrict__ edge_value,
                            const int* __restrict__ base, int* __restrict__ cur,
                            int* __restrict__ scol, float* __restrict__ sval) {
    int i = blockIdx.x * 256 + threadIdx.x;
    if (i >= NTOT) return;
    int j = i / NE;
    int e = i - j * NE;
    int row = edge_index[(size_t)j * 2 * NE + e];
    int col = edge_index[(size_t)j * 2 * NE + NE + e];
    int pos = base[row] + atomicAdd(&cur[row], 1);
    scol[pos] = col | (j << 17);
    sval[pos] = edge_value[(size_t)j * NE + e];
}

// ---------------- per-edge premultiplied weights for both layers ----------------
__global__ void wedge_kernel(const int* __restrict__ scol, const float* __restrict__ sval,
                             const float* __restrict__ filt, float2* __restrict__ wv0,
                             float2* __restrict__ wv1) {
    int k = blockIdx.x * 256 + threadIdx.x;
    if (k >= NTOT) return;
    int j = scol[k] >> 17;
    float ev = sval[k];
    float2 a, b;
    a.x = filt[j] * ev;               // layer0 c0
    a.y = filt[ETY + j] * ev;         // layer0 c1
    b.x = filt[2 * ETY + j] * ev;     // layer1 c0
    b.y = filt[3 * ETY + j] * ev;     // layer1 c1
    wv0[k] = a;
    wv1[k] = b;
}

// ---------------- gather: one wave per node, flat edge list, 4-deep MLP ----------------
__global__ void gather_kernel(const unsigned short* __restrict__ Hin, unsigned short* __restrict__ Hnew,
                              const int* __restrict__ base, const int* __restrict__ cnt,
                              const int* __restrict__ scol, const float2* __restrict__ wv) {
    const int lane = threadIdx.x & 63;
    const int wib  = threadIdx.x >> 6;
    const int n = blockIdx.x * 4 + wib;
    if (n >= NN) return;
    const unsigned short* hp = Hin + lane * 4;
    float a0 = 0.f, a1 = 0.f, a2 = 0.f, a3 = 0.f;
    int k = base[n];
    const int e = k + cnt[n];
    for (; k + 4 <= e; k += 4) {
        const int c0 = scol[k + 0] & COLMASK;
        const int c1 = scol[k + 1] & COLMASK;
        const int c2 = scol[k + 2] & COLMASK;
        const int c3 = scol[k + 3] & COLMASK;
        const float2 w0 = wv[k + 0];
        const float2 w1 = wv[k + 1];
        const float2 w2 = wv[k + 2];
        const float2 w3 = wv[k + 3];
        const ushort4 v0 = *(const ushort4*)(hp + (size_t)c0 * (WOUT * CCH));
        const ushort4 v1 = *(const ushort4*)(hp + (size_t)c1 * (WOUT * CCH));
        const ushort4 v2 = *(const ushort4*)(hp + (size_t)c2 * (WOUT * CCH));
        const ushort4 v3 = *(const ushort4*)(hp + (size_t)c3 * (WOUT * CCH));
        a0 = fmaf(w0.x, bf2f(v0.x), a0); a1 = fmaf(w0.y, bf2f(v0.y), a1);
        a2 = fmaf(w0.x, bf2f(v0.z), a2); a3 = fmaf(w0.y, bf2f(v0.w), a3);
        a0 = fmaf(w1.x, bf2f(v1.x), a0); a1 = fmaf(w1.y, bf2f(v1.y), a1);
        a2 = fmaf(w1.x, bf2f(v1.z), a2); a3 = fmaf(w1.y, bf2f(v1.w), a3);
        a0 = fmaf(w2.x, bf2f(v2.x), a0); a1 = fmaf(w2.y, bf2f(v2.y), a1);
        a2 = fmaf(w2.x, bf2f(v2.z), a2); a3 = fmaf(w2.y, bf2f(v2.w), a3);
        a0 = fmaf(w3.x, bf2f(v3.x), a0); a1 = fmaf(w3.y, bf2f(v3.y), a1);
        a2 = fmaf(w3.x, bf2f(v3.z), a2); a3 = fmaf(w3.y, bf2f(v3.w), a3);
    }
    for (; k < e; ++k) {
        const int c = scol[k] & COLMASK;
        const float2 w = wv[k];
        const ushort4 v = *(const ushort4*)(hp + (size_t)c * (WOUT * CCH));
        a0 = fmaf(w.x, bf2f(v.x), a0); a1 = fmaf(w.y, bf2f(v.y), a1);
        a2 = fmaf(w.x, bf2f(v.z), a2); a3 = fmaf(w.y, bf2f(v.w), a3);
    }
    ushort4 r4;
    r4.x = f2bf(a0); r4.y = f2bf(a1); r4.z = f2bf(a2); r4.w = f2bf(a3);
    *(ushort4*)(Hnew + (size_t)n * (WOUT * CCH) + lane * 4) = r4;
}

// ---------------- fused lin1+lin2 via bf16 MFMA, interleaved bf16 inputs ----------------
__global__ void lin_kernel(const unsigned short* __restrict__ Xpb, const unsigned short* __restrict__ Hb,
                           const unsigned short* __restrict__ w1b, const float* __restrict__ b1,
                           const float* __restrict__ w2, const float* __restrict__ b2,
                           float* __restrict__ out) {
    const int tid  = threadIdx.x;
    const int lane = tid & 63;
    const int wv   = tid >> 6;
    const int row0 = blockIdx.x * 64 + wv * 16;
    const int ar   = lane & 15;
    const int kg   = lane >> 4;
    int arow = row0 + ar; if (arow >= NN) arow = NN - 1;
    const unsigned short* xr = Xpb + (size_t)arow * (WOUT * CCH);
    const unsigned short* hr = Hb  + (size_t)arow * (WOUT * CCH);

    f32x4 acc[8];
#pragma unroll
    for (int nt = 0; nt < 8; ++nt) acc[nt] = (f32x4){0.f, 0.f, 0.f, 0.f};

    bf16x8 af1s[4];
#pragma unroll
    for (int kk = 0; kk < 4; ++kk) {
        const int d = kk * 32 + kg * 8;
        bf16x8 af0, af1;
#pragma unroll
        for (int t = 0; t < 4; ++t) {
            ushort4 xu = *(const ushort4*)(xr + 2 * d + 4 * t);
            ushort4 hu = *(const ushort4*)(hr + 2 * d + 4 * t);
            float v00 = fmaxf(0.1f * bf2f(xu.x) + 0.9f * bf2f(hu.x), 0.f);
            float v01 = fmaxf(0.1f * bf2f(xu.y) + 0.9f * bf2f(hu.y), 0.f);
            float v10 = fmaxf(0.1f * bf2f(xu.z) + 0.9f * bf2f(hu.z), 0.f);
            float v11 = fmaxf(0.1f * bf2f(xu.w) + 0.9f * bf2f(hu.w), 0.f);
            af0[2 * t]     = (short)f2bf(v00);
            af0[2 * t + 1] = (short)f2bf(v10);
            af1[2 * t]     = (short)f2bf(v01);
            af1[2 * t + 1] = (short)f2bf(v11);
        }
        af1s[kk] = af1;
        const int k0 = kk * 32 + kg * 8;
#pragma unroll
        for (int nt = 0; nt < 8; ++nt) {
            const bf16x8 bfm = *(const bf16x8*)(w1b + (size_t)(nt * 16 + ar) * (CCH * WOUT) + k0);
            acc[nt] = __builtin_amdgcn_mfma_f32_16x16x32_bf16(af0, bfm, acc[nt], 0, 0, 0);
        }
    }
#pragma unroll
    for (int kk = 4; kk < 8; ++kk) {
        const int k0 = kk * 32 + kg * 8;
        const bf16x8 af = af1s[kk - 4];
#pragma unroll
        for (int nt = 0; nt < 8; ++nt) {
            const bf16x8 bfm = *(const bf16x8*)(w1b + (size_t)(nt * 16 + ar) * (CCH * WOUT) + k0);
            acc[nt] = __builtin_amdgcn_mfma_f32_16x16x32_bf16(af, bfm, acc[nt], 0, 0, 0);
        }
    }

    float b1v[8], w2v[8][NCLS];
#pragma unroll
    for (int nt = 0; nt < 8; ++nt) {
        int col = nt * 16 + ar;
        b1v[nt] = b1[col];
#pragma unroll
        for (int m = 0; m < NCLS; ++m) w2v[nt][m] = w2[col * NCLS + m];
    }
#pragma unroll
    for (int q = 0; q < 4; ++q) {
        float pm[NCLS] = {0.f, 0.f, 0.f};
#pragma unroll
        for (int nt = 0; nt < 8; ++nt) {
            float h = acc[nt][q] + b1v[nt];
#pragma unroll
            for (int m = 0; m < NCLS; ++m) pm[m] = fmaf(h, w2v[nt][m], pm[m]);
        }
#pragma unroll
        for (int m = 0; m < NCLS; ++m) {
            pm[m] += __shfl_xor(pm[m], 1);
            pm[m] += __shfl_xor(pm[m], 2);
            pm[m] += __shfl_xor(pm[m], 4);
            pm[m] += __shfl_xor(pm[m], 8);
        }
        int r = row0 + kg * 4 + q;
        if (ar == 0 && r < NN) {
            out[(size_t)r * NCLS + 0] = pm[0] + b2[0];
            out[(size_t)r * NCLS + 1] = pm[1] + b2[1];
            out[(size_t)r * NCLS + 2] = pm[2] + b2[2];
        }
    }
}

extern "C" void kernel_launch(void* const* d_in, const int* in_sizes, int n_in,
                              void* d_out, int out_size, void* d_ws, size_t ws_size,
                              hipStream_t stream) {
    const int*   edge_index = (const int*)d_in[0];
    const float* edge_value = (const float*)d_in[1];
    const float* X          = (const float*)d_in[2];
    const float* Ws         = (const float*)d_in[3];
    const float* conv_w     = (const float*)d_in[4];
    const float* lin1_w     = (const float*)d_in[5];
    const float* lin1_b     = (const float*)d_in[6];
    const float* lin2_w     = (const float*)d_in[7];
    const float* lin2_b     = (const float*)d_in[8];
    float* out = (float*)d_out;

    const size_t CNU = (size_t)NN * WOUT * CCH;           // 25.6M ushorts per H buffer
    unsigned short* Xpb = (unsigned short*)d_ws;           // [N][128][2] bf16
    unsigned short* Ab  = Xpb + CNU;
    unsigned short* Bb  = Ab + CNU;
    float* filt = (float*)(Bb + CNU);                      // [L][C][ETY] pad 32
    int*   cnt  = (int*)(filt + 32);                       // [NN]
    int*   base = cnt + NN;
    int*   cur  = base + NN;
    int*   part = cur + NN;                                // [128]
    int*   scol = part + 128;                              // [NTOT] col | (j<<17)
    float* sval = (float*)(scol + NTOT);                   // [NTOT]
    float2* wv0 = (float2*)(sval + NTOT);                  // [NTOT]
    float2* wv1 = wv0 + NTOT;                              // [NTOT]
    unsigned short* Wsb = (unsigned short*)(wv1 + NTOT);   // [C][128][256] bf16
    unsigned short* w1b = Wsb + (size_t)CCH * WOUT * WIN;  // [128][256] bf16

    hipMemsetAsync(cnt, 0, NN * sizeof(int), stream);
    hipMemsetAsync(cur, 0, NN * sizeof(int), stream);

    filt_kernel<<<1, 64, 0, stream>>>(conv_w, filt);
    wconv_kernel<<<(CCH * WOUT * WIN + 255) / 256, 256, 0, stream>>>(Ws, lin1_w, Wsb, w1b);

    proj_kernel<<<(NN + 63) / 64, 256, 0, stream>>>(X, Wsb, Xpb);

    const int eblocks = (NTOT + 255) / 256;
    count_kernel<<<eblocks, 256, 0, stream>>>(edge_index, cnt);
    scan1_kernel<<<P_BLOCKS, 256, 0, stream>>>(cnt, part);
    scan2_kernel<<<1, 256, 0, stream>>>(part);
    scan3_kernel<<<P_BLOCKS, 256, 0, stream>>>(cnt, part, base);
    fill_kernel<<<eblocks, 256, 0, stream>>>(edge_index, edge_value, base, cur, scol, sval);
    wedge_kernel<<<eblocks, 256, 0, stream>>>(scol, sval, filt, wv0, wv1);

    const int gblocks = (NN + 3) / 4;
    gather_kernel<<<gblocks, 256, 0, stream>>>(Xpb, Ab, base, cnt, scol, wv0);
    gather_kernel<<<gblocks, 256, 0, stream>>>(Ab, Bb, base, cnt, scol, wv1);

    lin_kernel<<<(NN + 63) / 64, 256, 0, stream>>>(Xpb, Bb, w1b, lin1_b, lin2_w, lin2_b, out);
}

// Round 6
// 660.003 us; speedup vs baseline: 14.2874x; 1.2907x over previous
//
#include <hip/hip_runtime.h>

#define NN   100000   // num_nodes
#define ETY  5        // edge types
#define NE   500000   // edges per type
#define WIN  256
#define WOUT 128
#define CCH  2
#define LAY  2
#define NCLS 3

#define NTOT   (ETY * NE)             // 2500000 edges total
#define BSHIFT 7                      // 128 nodes per bucket
#define BNODES 128
#define NBUCK  ((NN + BNODES - 1) / BNODES)   // 782
#define BCAP   4096                   // capacity per bucket (mean ~3200, +15 sigma)
#define ACHUNK 8192

typedef __attribute__((ext_vector_type(8))) short bf16x8;
typedef __attribute__((ext_vector_type(4))) float f32x4;

__device__ __forceinline__ unsigned short f2bf(float f) {
    union { float f; unsigned u; } v; v.f = f;
    unsigned u = v.u + 0x7FFFu + ((v.u >> 16) & 1u);
    return (unsigned short)(u >> 16);
}
__device__ __forceinline__ float bf2f(unsigned short u) {
    union { unsigned u; float f; } v; v.u = ((unsigned)u) << 16;
    return v.f;
}

__device__ __forceinline__ bf16x8 pack8(float4 a, float4 b) {
    bf16x8 r;
    r[0] = (short)f2bf(a.x); r[1] = (short)f2bf(a.y);
    r[2] = (short)f2bf(a.z); r[3] = (short)f2bf(a.w);
    r[4] = (short)f2bf(b.x); r[5] = (short)f2bf(b.y);
    r[6] = (short)f2bf(b.z); r[7] = (short)f2bf(b.w);
    return r;
}

// ---------------- softmax over edge types for each (layer, channel) ----------------
__global__ void filt_kernel(const float* __restrict__ conv_w, float* __restrict__ filt) {
    int g = threadIdx.x;
    if (g < LAY * CCH) {
        float m = -1e30f;
        for (int j = 0; j < ETY; ++j) m = fmaxf(m, conv_w[g * ETY + j]);
        float e[ETY], s = 0.f;
        for (int j = 0; j < ETY; ++j) { e[j] = __expf(conv_w[g * ETY + j] - m); s += e[j]; }
        float inv = 1.f / s;
        for (int j = 0; j < ETY; ++j) filt[g * ETY + j] = e[j] * inv;
    }
}

// ---------------- weight conversion ----------------
__global__ void wconv_kernel(const float* __restrict__ Ws, const float* __restrict__ w1,
                             unsigned short* __restrict__ Wsb, unsigned short* __restrict__ w1b) {
    int i = blockIdx.x * 256 + threadIdx.x;
    if (i < CCH * WOUT * WIN) {
        int c = i / (WOUT * WIN);
        int r = i - c * WOUT * WIN;
        int n = r / WIN;
        int k = r - n * WIN;
        Wsb[i] = f2bf(Ws[((size_t)c * WIN + k) * WOUT + n]);
    }
    if (i < WOUT * (CCH * WOUT)) {
        int n = i / (CCH * WOUT);
        int k = i - n * (CCH * WOUT);
        w1b[i] = f2bf(w1[(size_t)k * WOUT + n]);
    }
}

// ---------------- Xpb[n][d][c] = (X @ Ws[c])[n][d] bf16 interleaved ----------------
__global__ void proj_kernel(const float* __restrict__ X, const unsigned short* __restrict__ Wsb,
                            unsigned short* __restrict__ Xpb) {
    const int tid  = threadIdx.x;
    const int lane = tid & 63;
    const int wv   = tid >> 6;
    const int row0 = blockIdx.x * 64 + wv * 16;
    const int ar   = lane & 15;
    const int kg   = lane >> 4;
    int arow = row0 + ar; if (arow >= NN) arow = NN - 1;
    const float* xrow = X + (size_t)arow * WIN + kg * 8;

    f32x4 acc[2][8];
#pragma unroll
    for (int c = 0; c < 2; ++c)
#pragma unroll
        for (int nt = 0; nt < 8; ++nt) acc[c][nt] = (f32x4){0.f, 0.f, 0.f, 0.f};

#pragma unroll
    for (int kk = 0; kk < 8; ++kk) {
        float4 a0 = *(const float4*)(xrow + kk * 32);
        float4 a1 = *(const float4*)(xrow + kk * 32 + 4);
        bf16x8 af = pack8(a0, a1);
#pragma unroll
        for (int c = 0; c < 2; ++c)
#pragma unroll
            for (int nt = 0; nt < 8; ++nt) {
                const bf16x8 bfm = *(const bf16x8*)(Wsb + (size_t)c * WOUT * WIN +
                                                    (size_t)(nt * 16 + ar) * WIN + kk * 32 + kg * 8);
                acc[c][nt] = __builtin_amdgcn_mfma_f32_16x16x32_bf16(af, bfm, acc[c][nt], 0, 0, 0);
            }
    }
#pragma unroll
    for (int nt = 0; nt < 8; ++nt) {
#pragma unroll
        for (int q = 0; q < 4; ++q) {
            int r = row0 + kg * 4 + q;
            if (r < NN) {
                int col = nt * 16 + ar;
                ushort2 w;
                w.x = f2bf(acc[0][nt][q]);
                w.y = f2bf(acc[1][nt][q]);
                *(ushort2*)(Xpb + (size_t)r * (WOUT * CCH) + col * 2) = w;
            }
        }
    }
}

// ---------------- Phase A: bucket edges by row>>7, LDS-aggregated range claims ----------------
__global__ void __launch_bounds__(256) bucket_kernel(const int* __restrict__ edge_index,
                                                     const float* __restrict__ edge_value,
                                                     int* __restrict__ bcur, int2* __restrict__ rec) {
    __shared__ int hist[NBUCK];
    __shared__ int start_s[NBUCK];
    const int tid = threadIdx.x;
    const int i0 = blockIdx.x * ACHUNK;
    int i1 = i0 + ACHUNK; if (i1 > NTOT) i1 = NTOT;
    for (int t = tid; t < NBUCK; t += 256) hist[t] = 0;
    __syncthreads();
    for (int i = i0 + tid; i < i1; i += 256) {
        int j = i / NE; int e = i - j * NE;
        int row = edge_index[(size_t)j * 2 * NE + e];
        atomicAdd(&hist[row >> BSHIFT], 1);
    }
    __syncthreads();
    for (int t = tid; t < NBUCK; t += 256) {
        int h = hist[t];
        start_s[t] = h ? atomicAdd(&bcur[t], h) : 0;
        hist[t] = 0;
    }
    __syncthreads();
    for (int i = i0 + tid; i < i1; i += 256) {
        int j = i / NE; int e = i - j * NE;
        int row = edge_index[(size_t)j * 2 * NE + e];
        int col = edge_index[(size_t)j * 2 * NE + NE + e];
        int bk = row >> BSHIFT;
        int p = start_s[bk] + atomicAdd(&hist[bk], 1);
        if (p < BCAP)
            rec[(size_t)bk * BCAP + p] =
                make_int2(col | (j << 17) | ((row & (BNODES - 1)) << 20), __float_as_int(edge_value[i]));
    }
}

// ---------------- Phase B: per-bucket LDS sort by node + emit col/wv0/wv1 + node base/cnt ----------------
__global__ void __launch_bounds__(256) sortb_kernel(const int2* __restrict__ rec,
                                                    const int* __restrict__ bcur,
                                                    const float* __restrict__ filt,
                                                    int* __restrict__ colF, float2* __restrict__ wv0F,
                                                    float2* __restrict__ wv1F, int* __restrict__ baseF,
                                                    int* __restrict__ cntF) {
    __shared__ int nh[BNODES];       // counts, then running cursors
    __shared__ int nb[BNODES + 1];   // exclusive bases
    __shared__ int2 srec[BCAP];      // 32 KB staging
    __shared__ float fl[4 * ETY];
    const int b = blockIdx.x;
    const int tid = threadIdx.x;
    int cnt = bcur[b]; if (cnt > BCAP) cnt = BCAP;
    if (tid < BNODES) nh[tid] = 0;
    if (tid < 4 * ETY) fl[tid] = filt[tid];
    __syncthreads();
    const int2* rb = rec + (size_t)b * BCAP;
    for (int k = tid; k < cnt; k += 256) {
        int r = (rb[k].x >> 20) & (BNODES - 1);
        atomicAdd(&nh[r], 1);
    }
    __syncthreads();
    if (tid < BNODES) nb[tid + 1] = nh[tid];
    if (tid == 0) nb[0] = 0;
    __syncthreads();
    for (int off = 1; off < BNODES; off <<= 1) {
        int v = 0;
        if (tid < BNODES) { v = nb[tid + 1]; if (tid + 1 > off) v += nb[tid + 1 - off]; }
        __syncthreads();
        if (tid < BNODES) nb[tid + 1] = v;
        __syncthreads();
    }
    if (tid < BNODES) nh[tid] = 0;
    __syncthreads();
    for (int k = tid; k < cnt; k += 256) {
        int2 R = rb[k];
        int r = (R.x >> 20) & (BNODES - 1);
        int p = nb[r] + atomicAdd(&nh[r], 1);
        srec[p] = R;
    }
    __syncthreads();
    const size_t g0 = (size_t)b * BCAP;
    for (int k = tid; k < cnt; k += 256) {
        int2 R = srec[k];
        int col = R.x & 0x1FFFF;
        int j = (R.x >> 17) & 7;
        float ev = __int_as_float(R.y);
        colF[g0 + k] = col;
        wv0F[g0 + k] = make_float2(fl[j] * ev, fl[ETY + j] * ev);
        wv1F[g0 + k] = make_float2(fl[2 * ETY + j] * ev, fl[3 * ETY + j] * ev);
    }
    if (tid < BNODES) {
        int n = b * BNODES + tid;
        if (n < NN) {
            baseF[n] = (int)(g0 + nb[tid]);
            cntF[n]  = nb[tid + 1] - nb[tid];
        }
    }
}

// ---------------- gather: one wave per node, flat per-node edge list, 4-deep MLP ----------------
__global__ void gather_kernel(const unsigned short* __restrict__ Hin, unsigned short* __restrict__ Hnew,
                              const int* __restrict__ base, const int* __restrict__ cnt,
                              const int* __restrict__ colF, const float2* __restrict__ wv) {
    const int lane = threadIdx.x & 63;
    const int wib  = threadIdx.x >> 6;
    const int n = blockIdx.x * 4 + wib;
    if (n >= NN) return;
    const unsigned short* hp = Hin + lane * 4;
    float a0 = 0.f, a1 = 0.f, a2 = 0.f, a3 = 0.f;
    int k = base[n];
    const int e = k + cnt[n];
    for (; k + 4 <= e; k += 4) {
        const int c0 = colF[k + 0];
        const int c1 = colF[k + 1];
        const int c2 = colF[k + 2];
        const int c3 = colF[k + 3];
        const float2 w0 = wv[k + 0];
        const float2 w1 = wv[k + 1];
        const float2 w2 = wv[k + 2];
        const float2 w3 = wv[k + 3];
        const ushort4 v0 = *(const ushort4*)(hp + (size_t)c0 * (WOUT * CCH));
        const ushort4 v1 = *(const ushort4*)(hp + (size_t)c1 * (WOUT * CCH));
        const ushort4 v2 = *(const ushort4*)(hp + (size_t)c2 * (WOUT * CCH));
        const ushort4 v3 = *(const ushort4*)(hp + (size_t)c3 * (WOUT * CCH));
        a0 = fmaf(w0.x, bf2f(v0.x), a0); a1 = fmaf(w0.y, bf2f(v0.y), a1);
        a2 = fmaf(w0.x, bf2f(v0.z), a2); a3 = fmaf(w0.y, bf2f(v0.w), a3);
        a0 = fmaf(w1.x, bf2f(v1.x), a0); a1 = fmaf(w1.y, bf2f(v1.y), a1);
        a2 = fmaf(w1.x, bf2f(v1.z), a2); a3 = fmaf(w1.y, bf2f(v1.w), a3);
        a0 = fmaf(w2.x, bf2f(v2.x), a0); a1 = fmaf(w2.y, bf2f(v2.y), a1);
        a2 = fmaf(w2.x, bf2f(v2.z), a2); a3 = fmaf(w2.y, bf2f(v2.w), a3);
        a0 = fmaf(w3.x, bf2f(v3.x), a0); a1 = fmaf(w3.y, bf2f(v3.y), a1);
        a2 = fmaf(w3.x, bf2f(v3.z), a2); a3 = fmaf(w3.y, bf2f(v3.w), a3);
    }
    for (; k < e; ++k) {
        const int c = colF[k];
        const float2 w = wv[k];
        const ushort4 v = *(const ushort4*)(hp + (size_t)c * (WOUT * CCH));
        a0 = fmaf(w.x, bf2f(v.x), a0); a1 = fmaf(w.y, bf2f(v.y), a1);
        a2 = fmaf(w.x, bf2f(v.z), a2); a3 = fmaf(w.y, bf2f(v.w), a3);
    }
    ushort4 r4;
    r4.x = f2bf(a0); r4.y = f2bf(a1); r4.z = f2bf(a2); r4.w = f2bf(a3);
    *(ushort4*)(Hnew + (size_t)n * (WOUT * CCH) + lane * 4) = r4;
}

// ---------------- fused lin1+lin2 via bf16 MFMA, interleaved bf16 inputs ----------------
__global__ void lin_kernel(const unsigned short* __restrict__ Xpb, const unsigned short* __restrict__ Hb,
                           const unsigned short* __restrict__ w1b, const float* __restrict__ b1,
                           const float* __restrict__ w2, const float* __restrict__ b2,
                           float* __restrict__ out) {
    const int tid  = threadIdx.x;
    const int lane = tid & 63;
    const int wv   = tid >> 6;
    const int row0 = blockIdx.x * 64 + wv * 16;
    const int ar   = lane & 15;
    const int kg   = lane >> 4;
    int arow = row0 + ar; if (arow >= NN) arow = NN - 1;
    const unsigned short* xr = Xpb + (size_t)arow * (WOUT * CCH);
    const unsigned short* hr = Hb  + (size_t)arow * (WOUT * CCH);

    f32x4 acc[8];
#pragma unroll
    for (int nt = 0; nt < 8; ++nt) acc[nt] = (f32x4){0.f, 0.f, 0.f, 0.f};

    bf16x8 af1s[4];
#pragma unroll
    for (int kk = 0; kk < 4; ++kk) {
        const int d = kk * 32 + kg * 8;
        bf16x8 af0, af1;
#pragma unroll
        for (int t = 0; t < 4; ++t) {
            ushort4 xu = *(const ushort4*)(xr + 2 * d + 4 * t);
            ushort4 hu = *(const ushort4*)(hr + 2 * d + 4 * t);
            float v00 = fmaxf(0.1f * bf2f(xu.x) + 0.9f * bf2f(hu.x), 0.f);
            float v01 = fmaxf(0.1f * bf2f(xu.y) + 0.9f * bf2f(hu.y), 0.f);
            float v10 = fmaxf(0.1f * bf2f(xu.z) + 0.9f * bf2f(hu.z), 0.f);
            float v11 = fmaxf(0.1f * bf2f(xu.w) + 0.9f * bf2f(hu.w), 0.f);
            af0[2 * t]     = (short)f2bf(v00);
            af0[2 * t + 1] = (short)f2bf(v10);
            af1[2 * t]     = (short)f2bf(v01);
            af1[2 * t + 1] = (short)f2bf(v11);
        }
        af1s[kk] = af1;
        const int k0 = kk * 32 + kg * 8;
#pragma unroll
        for (int nt = 0; nt < 8; ++nt) {
            const bf16x8 bfm = *(const bf16x8*)(w1b + (size_t)(nt * 16 + ar) * (CCH * WOUT) + k0);
            acc[nt] = __builtin_amdgcn_mfma_f32_16x16x32_bf16(af0, bfm, acc[nt], 0, 0, 0);
        }
    }
#pragma unroll
    for (int kk = 4; kk < 8; ++kk) {
        const int k0 = kk * 32 + kg * 8;
        const bf16x8 af = af1s[kk - 4];
#pragma unroll
        for (int nt = 0; nt < 8; ++nt) {
            const bf16x8 bfm = *(const bf16x8*)(w1b + (size_t)(nt * 16 + ar) * (CCH * WOUT) + k0);
            acc[nt] = __builtin_amdgcn_mfma_f32_16x16x32_bf16(af, bfm, acc[nt], 0, 0, 0);
        }
    }

    float b1v[8], w2v[8][NCLS];
#pragma unroll
    for (int nt = 0; nt < 8; ++nt) {
        int col = nt * 16 + ar;
        b1v[nt] = b1[col];
#pragma unroll
        for (int m = 0; m < NCLS; ++m) w2v[nt][m] = w2[col * NCLS + m];
    }
#pragma unroll
    for (int q = 0; q < 4; ++q) {
        float pm[NCLS] = {0.f, 0.f, 0.f};
#pragma unroll
        for (int nt = 0; nt < 8; ++nt) {
            float h = acc[nt][q] + b1v[nt];
#pragma unroll
            for (int m = 0; m < NCLS; ++m) pm[m] = fmaf(h, w2v[nt][m], pm[m]);
        }
#pragma unroll
        for (int m = 0; m < NCLS; ++m) {
            pm[m] += __shfl_xor(pm[m], 1);
            pm[m] += __shfl_xor(pm[m], 2);
            pm[m] += __shfl_xor(pm[m], 4);
            pm[m] += __shfl_xor(pm[m], 8);
        }
        int r = row0 + kg * 4 + q;
        if (ar == 0 && r < NN) {
            out[(size_t)r * NCLS + 0] = pm[0] + b2[0];
            out[(size_t)r * NCLS + 1] = pm[1] + b2[1];
            out[(size_t)r * NCLS + 2] = pm[2] + b2[2];
        }
    }
}

extern "C" void kernel_launch(void* const* d_in, const int* in_sizes, int n_in,
                              void* d_out, int out_size, void* d_ws, size_t ws_size,
                              hipStream_t stream) {
    const int*   edge_index = (const int*)d_in[0];
    const float* edge_value = (const float*)d_in[1];
    const float* X          = (const float*)d_in[2];
    const float* Ws         = (const float*)d_in[3];
    const float* conv_w     = (const float*)d_in[4];
    const float* lin1_w     = (const float*)d_in[5];
    const float* lin1_b     = (const float*)d_in[6];
    const float* lin2_w     = (const float*)d_in[7];
    const float* lin2_b     = (const float*)d_in[8];
    float* out = (float*)d_out;

    const size_t CNU  = (size_t)NN * WOUT * CCH;          // 25.6M ushorts per H buffer
    const size_t SLOT = (size_t)NBUCK * BCAP;             // 3.2M edge slots (with holes)
    unsigned short* Xpb = (unsigned short*)d_ws;           // [N][128][2] bf16
    unsigned short* Ab  = Xpb + CNU;
    unsigned short* Bb  = Ab + CNU;
    float*  filt = (float*)(Bb + CNU);                     // [L][C][ETY] pad 32
    int*    bcur = (int*)(filt + 32);                      // [NBUCK]
    int*    baseF = bcur + NBUCK;                          // [NN]
    int*    cntF  = baseF + NN;                            // [NN]
    int2*   rec   = (int2*)(cntF + NN);                    // [SLOT] packed records
    int*    colF  = (int*)(rec + SLOT);                    // [SLOT]
    float2* wv0F  = (float2*)(colF + SLOT);                // [SLOT]
    float2* wv1F  = wv0F + SLOT;                           // [SLOT]
    unsigned short* Wsb = (unsigned short*)(wv1F + SLOT);  // [C][128][256] bf16
    unsigned short* w1b = Wsb + (size_t)CCH * WOUT * WIN;  // [128][256] bf16

    hipMemsetAsync(bcur, 0, NBUCK * sizeof(int), stream);

    filt_kernel<<<1, 64, 0, stream>>>(conv_w, filt);
    wconv_kernel<<<(CCH * WOUT * WIN + 255) / 256, 256, 0, stream>>>(Ws, lin1_w, Wsb, w1b);

    proj_kernel<<<(NN + 63) / 64, 256, 0, stream>>>(X, Wsb, Xpb);

    bucket_kernel<<<(NTOT + ACHUNK - 1) / ACHUNK, 256, 0, stream>>>(edge_index, edge_value, bcur, rec);
    sortb_kernel<<<NBUCK, 256, 0, stream>>>(rec, bcur, filt, colF, wv0F, wv1F, baseF, cntF);

    const int gblocks = (NN + 3) / 4;
    gather_kernel<<<gblocks, 256, 0, stream>>>(Xpb, Ab, baseF, cntF, colF, wv0F);
    gather_kernel<<<gblocks, 256, 0, stream>>>(Ab, Bb, baseF, cntF, colF, wv1F);

    lin_kernel<<<(NN + 63) / 64, 256, 0, stream>>>(Xpb, Bb, w1b, lin1_b, lin2_w, lin2_b, out);
}

// Round 7
// 653.037 us; speedup vs baseline: 14.4398x; 1.0107x over previous
//
#include <hip/hip_runtime.h>

#define NN   100000   // num_nodes
#define ETY  5        // edge types
#define NE   500000   // edges per type
#define WIN  256
#define WOUT 128
#define CCH  2
#define LAY  2
#define NCLS 3

#define NTOT   (ETY * NE)             // 2500000 edges total
#define BSHIFT 7                      // 128 nodes per bucket
#define BNODES 128
#define NBUCK  ((NN + BNODES - 1) / BNODES)   // 782
#define BCAP   4096                   // capacity per bucket (mean ~3200)
#define ACHUNK 8192

typedef __attribute__((ext_vector_type(8))) short bf16x8;
typedef __attribute__((ext_vector_type(4))) float f32x4;

__device__ __forceinline__ unsigned short f2bf(float f) {
    union { float f; unsigned u; } v; v.f = f;
    unsigned u = v.u + 0x7FFFu + ((v.u >> 16) & 1u);
    return (unsigned short)(u >> 16);
}
__device__ __forceinline__ float bf2f(unsigned short u) {
    union { unsigned u; float f; } v; v.u = ((unsigned)u) << 16;
    return v.f;
}

__device__ __forceinline__ bf16x8 pack8(float4 a, float4 b) {
    bf16x8 r;
    r[0] = (short)f2bf(a.x); r[1] = (short)f2bf(a.y);
    r[2] = (short)f2bf(a.z); r[3] = (short)f2bf(a.w);
    r[4] = (short)f2bf(b.x); r[5] = (short)f2bf(b.y);
    r[6] = (short)f2bf(b.z); r[7] = (short)f2bf(b.w);
    return r;
}

// ---------------- softmax over edge types for each (layer, channel) ----------------
__global__ void filt_kernel(const float* __restrict__ conv_w, float* __restrict__ filt) {
    int g = threadIdx.x;
    if (g < LAY * CCH) {
        float m = -1e30f;
        for (int j = 0; j < ETY; ++j) m = fmaxf(m, conv_w[g * ETY + j]);
        float e[ETY], s = 0.f;
        for (int j = 0; j < ETY; ++j) { e[j] = __expf(conv_w[g * ETY + j] - m); s += e[j]; }
        float inv = 1.f / s;
        for (int j = 0; j < ETY; ++j) filt[g * ETY + j] = e[j] * inv;
    }
}

// ---------------- weight conversion ----------------
__global__ void wconv_kernel(const float* __restrict__ Ws, const float* __restrict__ w1,
                             unsigned short* __restrict__ Wsb, unsigned short* __restrict__ w1b) {
    int i = blockIdx.x * 256 + threadIdx.x;
    if (i < CCH * WOUT * WIN) {
        int c = i / (WOUT * WIN);
        int r = i - c * WOUT * WIN;
        int n = r / WIN;
        int k = r - n * WIN;
        Wsb[i] = f2bf(Ws[((size_t)c * WIN + k) * WOUT + n]);
    }
    if (i < WOUT * (CCH * WOUT)) {
        int n = i / (CCH * WOUT);
        int k = i - n * (CCH * WOUT);
        w1b[i] = f2bf(w1[(size_t)k * WOUT + n]);
    }
}

// ---------------- Xpb[n][d][c] = (X @ Ws[c])[n][d] bf16 interleaved ----------------
__global__ void proj_kernel(const float* __restrict__ X, const unsigned short* __restrict__ Wsb,
                            unsigned short* __restrict__ Xpb) {
    const int tid  = threadIdx.x;
    const int lane = tid & 63;
    const int wv   = tid >> 6;
    const int row0 = blockIdx.x * 64 + wv * 16;
    const int ar   = lane & 15;
    const int kg   = lane >> 4;
    int arow = row0 + ar; if (arow >= NN) arow = NN - 1;
    const float* xrow = X + (size_t)arow * WIN + kg * 8;

    f32x4 acc[2][8];
#pragma unroll
    for (int c = 0; c < 2; ++c)
#pragma unroll
        for (int nt = 0; nt < 8; ++nt) acc[c][nt] = (f32x4){0.f, 0.f, 0.f, 0.f};

#pragma unroll
    for (int kk = 0; kk < 8; ++kk) {
        float4 a0 = *(const float4*)(xrow + kk * 32);
        float4 a1 = *(const float4*)(xrow + kk * 32 + 4);
        bf16x8 af = pack8(a0, a1);
#pragma unroll
        for (int c = 0; c < 2; ++c)
#pragma unroll
            for (int nt = 0; nt < 8; ++nt) {
                const bf16x8 bfm = *(const bf16x8*)(Wsb + (size_t)c * WOUT * WIN +
                                                    (size_t)(nt * 16 + ar) * WIN + kk * 32 + kg * 8);
                acc[c][nt] = __builtin_amdgcn_mfma_f32_16x16x32_bf16(af, bfm, acc[c][nt], 0, 0, 0);
            }
    }
#pragma unroll
    for (int nt = 0; nt < 8; ++nt) {
#pragma unroll
        for (int q = 0; q < 4; ++q) {
            int r = row0 + kg * 4 + q;
            if (r < NN) {
                int col = nt * 16 + ar;
                ushort2 w;
                w.x = f2bf(acc[0][nt][q]);
                w.y = f2bf(acc[1][nt][q]);
                *(ushort2*)(Xpb + (size_t)r * (WOUT * CCH) + col * 2) = w;
            }
        }
    }
}

// ---------------- Phase A: bucket edges by row>>7, LDS-aggregated range claims ----------------
__global__ void __launch_bounds__(256) bucket_kernel(const int* __restrict__ edge_index,
                                                     const float* __restrict__ edge_value,
                                                     int* __restrict__ bcur, int2* __restrict__ rec) {
    __shared__ int hist[NBUCK];
    __shared__ int start_s[NBUCK];
    const int tid = threadIdx.x;
    const int i0 = blockIdx.x * ACHUNK;
    int i1 = i0 + ACHUNK; if (i1 > NTOT) i1 = NTOT;
    for (int t = tid; t < NBUCK; t += 256) hist[t] = 0;
    __syncthreads();
    for (int i = i0 + tid; i < i1; i += 256) {
        int j = i / NE; int e = i - j * NE;
        int row = edge_index[(size_t)j * 2 * NE + e];
        atomicAdd(&hist[row >> BSHIFT], 1);
    }
    __syncthreads();
    for (int t = tid; t < NBUCK; t += 256) {
        int h = hist[t];
        start_s[t] = h ? atomicAdd(&bcur[t], h) : 0;
        hist[t] = 0;
    }
    __syncthreads();
    for (int i = i0 + tid; i < i1; i += 256) {
        int j = i / NE; int e = i - j * NE;
        int row = edge_index[(size_t)j * 2 * NE + e];
        int col = edge_index[(size_t)j * 2 * NE + NE + e];
        int bk = row >> BSHIFT;
        int p = start_s[bk] + atomicAdd(&hist[bk], 1);
        if (p < BCAP)
            rec[(size_t)bk * BCAP + p] =
                make_int2(col | (j << 17) | ((row & (BNODES - 1)) << 20), __float_as_int(edge_value[i]));
    }
}

// ---------------- Phase B: per-bucket LDS sort by node + emit col/wv0/wv1 + node base/cnt ----------------
__global__ void __launch_bounds__(256) sortb_kernel(const int2* __restrict__ rec,
                                                    const int* __restrict__ bcur,
                                                    const float* __restrict__ filt,
                                                    int* __restrict__ colF, float2* __restrict__ wv0F,
                                                    float2* __restrict__ wv1F, int* __restrict__ baseF,
                                                    int* __restrict__ cntF) {
    __shared__ int nh[BNODES];
    __shared__ int nb[BNODES + 1];
    __shared__ int2 srec[BCAP];
    __shared__ float fl[4 * ETY];
    const int b = blockIdx.x;
    const int tid = threadIdx.x;
    int cnt = bcur[b]; if (cnt > BCAP) cnt = BCAP;
    if (tid < BNODES) nh[tid] = 0;
    if (tid < 4 * ETY) fl[tid] = filt[tid];
    __syncthreads();
    const int2* rb = rec + (size_t)b * BCAP;
    for (int k = tid; k < cnt; k += 256) {
        int r = (rb[k].x >> 20) & (BNODES - 1);
        atomicAdd(&nh[r], 1);
    }
    __syncthreads();
    if (tid < BNODES) nb[tid + 1] = nh[tid];
    if (tid == 0) nb[0] = 0;
    __syncthreads();
    for (int off = 1; off < BNODES; off <<= 1) {
        int v = 0;
        if (tid < BNODES) { v = nb[tid + 1]; if (tid + 1 > off) v += nb[tid + 1 - off]; }
        __syncthreads();
        if (tid < BNODES) nb[tid + 1] = v;
        __syncthreads();
    }
    if (tid < BNODES) nh[tid] = 0;
    __syncthreads();
    for (int k = tid; k < cnt; k += 256) {
        int2 R = rb[k];
        int r = (R.x >> 20) & (BNODES - 1);
        int p = nb[r] + atomicAdd(&nh[r], 1);
        srec[p] = R;
    }
    __syncthreads();
    const size_t g0 = (size_t)b * BCAP;
    for (int k = tid; k < cnt; k += 256) {
        int2 R = srec[k];
        int col = R.x & 0x1FFFF;
        int j = (R.x >> 17) & 7;
        float ev = __int_as_float(R.y);
        colF[g0 + k] = col;
        wv0F[g0 + k] = make_float2(fl[j] * ev, fl[ETY + j] * ev);
        wv1F[g0 + k] = make_float2(fl[2 * ETY + j] * ev, fl[3 * ETY + j] * ev);
    }
    if (tid < BNODES) {
        int n = b * BNODES + tid;
        if (n < NN) {
            baseF[n] = (int)(g0 + nb[tid]);
            cntF[n]  = nb[tid + 1] - nb[tid];
        }
    }
}

// ---------------- gather: one wave per node, scalar edge metadata, 8-deep gather MLP ----------------
__global__ void gather_kernel(const unsigned short* __restrict__ Hin, unsigned short* __restrict__ Hnew,
                              const int* __restrict__ base, const int* __restrict__ cnt,
                              const int* __restrict__ colF, const float2* __restrict__ wv) {
    const int lane = threadIdx.x & 63;
    const int wib  = threadIdx.x >> 6;
    int n0 = blockIdx.x * 4 + wib;
    if (n0 >= NN) return;
    const int n = __builtin_amdgcn_readfirstlane(n0);   // force SGPR -> scalar loads below
    const unsigned short* hp = Hin + lane * 4;
    float a0 = 0.f, a1 = 0.f, a2 = 0.f, a3 = 0.f;
    const int kb = __builtin_amdgcn_readfirstlane(base[n]);
    const int ce = __builtin_amdgcn_readfirstlane(cnt[n]);
    const int e = kb + ce;
    for (int k = kb; k < e; k += 8) {
        int cs[8];
#pragma unroll
        for (int u = 0; u < 8; ++u) {
            int ku = k + u;
            cs[u] = colF[ku < e ? ku : e - 1];           // uniform (scalar) load
        }
        ushort4 vs[8];
#pragma unroll
        for (int u = 0; u < 8; ++u)                      // 8 independent gathers in flight
            vs[u] = *(const ushort4*)(hp + (size_t)cs[u] * (WOUT * CCH));
        float2 ws[8];
#pragma unroll
        for (int u = 0; u < 8; ++u) {
            int ku = k + u;
            float2 w = wv[ku < e ? ku : e - 1];          // uniform (scalar) load
            if (ku >= e) { w.x = 0.f; w.y = 0.f; }
            ws[u] = w;
        }
#pragma unroll
        for (int u = 0; u < 8; ++u) {
            a0 = fmaf(ws[u].x, bf2f(vs[u].x), a0);
            a1 = fmaf(ws[u].y, bf2f(vs[u].y), a1);
            a2 = fmaf(ws[u].x, bf2f(vs[u].z), a2);
            a3 = fmaf(ws[u].y, bf2f(vs[u].w), a3);
        }
    }
    ushort4 r4;
    r4.x = f2bf(a0); r4.y = f2bf(a1); r4.z = f2bf(a2); r4.w = f2bf(a3);
    *(ushort4*)(Hnew + (size_t)n * (WOUT * CCH) + lane * 4) = r4;
}

// ---------------- fused lin1+lin2 via bf16 MFMA, interleaved bf16 inputs ----------------
__global__ void lin_kernel(const unsigned short* __restrict__ Xpb, const unsigned short* __restrict__ Hb,
                           const unsigned short* __restrict__ w1b, const float* __restrict__ b1,
                           const float* __restrict__ w2, const float* __restrict__ b2,
                           float* __restrict__ out) {
    const int tid  = threadIdx.x;
    const int lane = tid & 63;
    const int wv   = tid >> 6;
    const int row0 = blockIdx.x * 64 + wv * 16;
    const int ar   = lane & 15;
    const int kg   = lane >> 4;
    int arow = row0 + ar; if (arow >= NN) arow = NN - 1;
    const unsigned short* xr = Xpb + (size_t)arow * (WOUT * CCH);
    const unsigned short* hr = Hb  + (size_t)arow * (WOUT * CCH);

    f32x4 acc[8];
#pragma unroll
    for (int nt = 0; nt < 8; ++nt) acc[nt] = (f32x4){0.f, 0.f, 0.f, 0.f};

    bf16x8 af1s[4];
#pragma unroll
    for (int kk = 0; kk < 4; ++kk) {
        const int d = kk * 32 + kg * 8;
        bf16x8 af0, af1;
#pragma unroll
        for (int t = 0; t < 4; ++t) {
            ushort4 xu = *(const ushort4*)(xr + 2 * d + 4 * t);
            ushort4 hu = *(const ushort4*)(hr + 2 * d + 4 * t);
            float v00 = fmaxf(0.1f * bf2f(xu.x) + 0.9f * bf2f(hu.x), 0.f);
            float v01 = fmaxf(0.1f * bf2f(xu.y) + 0.9f * bf2f(hu.y), 0.f);
            float v10 = fmaxf(0.1f * bf2f(xu.z) + 0.9f * bf2f(hu.z), 0.f);
            float v11 = fmaxf(0.1f * bf2f(xu.w) + 0.9f * bf2f(hu.w), 0.f);
            af0[2 * t]     = (short)f2bf(v00);
            af0[2 * t + 1] = (short)f2bf(v10);
            af1[2 * t]     = (short)f2bf(v01);
            af1[2 * t + 1] = (short)f2bf(v11);
        }
        af1s[kk] = af1;
        const int k0 = kk * 32 + kg * 8;
#pragma unroll
        for (int nt = 0; nt < 8; ++nt) {
            const bf16x8 bfm = *(const bf16x8*)(w1b + (size_t)(nt * 16 + ar) * (CCH * WOUT) + k0);
            acc[nt] = __builtin_amdgcn_mfma_f32_16x16x32_bf16(af0, bfm, acc[nt], 0, 0, 0);
        }
    }
#pragma unroll
    for (int kk = 4; kk < 8; ++kk) {
        const int k0 = kk * 32 + kg * 8;
        const bf16x8 af = af1s[kk - 4];
#pragma unroll
        for (int nt = 0; nt < 8; ++nt) {
            const bf16x8 bfm = *(const bf16x8*)(w1b + (size_t)(nt * 16 + ar) * (CCH * WOUT) + k0);
            acc[nt] = __builtin_amdgcn_mfma_f32_16x16x32_bf16(af, bfm, acc[nt], 0, 0, 0);
        }
    }

    float b1v[8], w2v[8][NCLS];
#pragma unroll
    for (int nt = 0; nt < 8; ++nt) {
        int col = nt * 16 + ar;
        b1v[nt] = b1[col];
#pragma unroll
        for (int m = 0; m < NCLS; ++m) w2v[nt][m] = w2[col * NCLS + m];
    }
#pragma unroll
    for (int q = 0; q < 4; ++q) {
        float pm[NCLS] = {0.f, 0.f, 0.f};
#pragma unroll
        for (int nt = 0; nt < 8; ++nt) {
            float h = acc[nt][q] + b1v[nt];
#pragma unroll
            for (int m = 0; m < NCLS; ++m) pm[m] = fmaf(h, w2v[nt][m], pm[m]);
        }
#pragma unroll
        for (int m = 0; m < NCLS; ++m) {
            pm[m] += __shfl_xor(pm[m], 1);
            pm[m] += __shfl_xor(pm[m], 2);
            pm[m] += __shfl_xor(pm[m], 4);
            pm[m] += __shfl_xor(pm[m], 8);
        }
        int r = row0 + kg * 4 + q;
        if (ar == 0 && r < NN) {
            out[(size_t)r * NCLS + 0] = pm[0] + b2[0];
            out[(size_t)r * NCLS + 1] = pm[1] + b2[1];
            out[(size_t)r * NCLS + 2] = pm[2] + b2[2];
        }
    }
}

extern "C" void kernel_launch(void* const* d_in, const int* in_sizes, int n_in,
                              void* d_out, int out_size, void* d_ws, size_t ws_size,
                              hipStream_t stream) {
    const int*   edge_index = (const int*)d_in[0];
    const float* edge_value = (const float*)d_in[1];
    const float* X          = (const float*)d_in[2];
    const float* Ws         = (const float*)d_in[3];
    const float* conv_w     = (const float*)d_in[4];
    const float* lin1_w     = (const float*)d_in[5];
    const float* lin1_b     = (const float*)d_in[6];
    const float* lin2_w     = (const float*)d_in[7];
    const float* lin2_b     = (const float*)d_in[8];
    float* out = (float*)d_out;

    const size_t CNU  = (size_t)NN * WOUT * CCH;
    const size_t SLOT = (size_t)NBUCK * BCAP;
    unsigned short* Xpb = (unsigned short*)d_ws;
    unsigned short* Ab  = Xpb + CNU;
    unsigned short* Bb  = Ab + CNU;
    float*  filt = (float*)(Bb + CNU);
    int*    bcur = (int*)(filt + 32);
    int*    baseF = bcur + NBUCK;
    int*    cntF  = baseF + NN;
    int2*   rec   = (int2*)(cntF + NN);
    int*    colF  = (int*)(rec + SLOT);
    float2* wv0F  = (float2*)(colF + SLOT);
    float2* wv1F  = wv0F + SLOT;
    unsigned short* Wsb = (unsigned short*)(wv1F + SLOT);
    unsigned short* w1b = Wsb + (size_t)CCH * WOUT * WIN;

    hipMemsetAsync(bcur, 0, NBUCK * sizeof(int), stream);

    filt_kernel<<<1, 64, 0, stream>>>(conv_w, filt);
    wconv_kernel<<<(CCH * WOUT * WIN + 255) / 256, 256, 0, stream>>>(Ws, lin1_w, Wsb, w1b);

    proj_kernel<<<(NN + 63) / 64, 256, 0, stream>>>(X, Wsb, Xpb);

    bucket_kernel<<<(NTOT + ACHUNK - 1) / ACHUNK, 256, 0, stream>>>(edge_index, edge_value, bcur, rec);
    sortb_kernel<<<NBUCK, 256, 0, stream>>>(rec, bcur, filt, colF, wv0F, wv1F, baseF, cntF);

    const int gblocks = (NN + 3) / 4;
    gather_kernel<<<gblocks, 256, 0, stream>>>(Xpb, Ab, baseF, cntF, colF, wv0F);
    gather_kernel<<<gblocks, 256, 0, stream>>>(Ab, Bb, baseF, cntF, colF, wv1F);

    lin_kernel<<<(NN + 63) / 64, 256, 0, stream>>>(Xpb, Bb, w1b, lin1_b, lin2_w, lin2_b, out);
}

// Round 8
// 641.603 us; speedup vs baseline: 14.6971x; 1.0178x over previous
//
#include <hip/hip_runtime.h>

#define NN   100000   // num_nodes
#define ETY  5        // edge types
#define NE   500000   // edges per type
#define WIN  256
#define WOUT 128
#define CCH  2
#define LAY  2
#define NCLS 3

#define NTOT   (ETY * NE)             // 2500000 edges total
#define BSHIFT 7                      // 128 nodes per bucket
#define BNODES 128
#define NBUCK  ((NN + BNODES - 1) / BNODES)   // 782
#define BCAP   4096                   // capacity per bucket (mean ~3200)
#define ACHUNK 8192
#define ABLK   ((NE + ACHUNK - 1) / ACHUNK)   // 62

typedef __attribute__((ext_vector_type(8))) short bf16x8;
typedef __attribute__((ext_vector_type(4))) float f32x4;

__device__ __forceinline__ unsigned short f2bf(float f) {
    union { float f; unsigned u; } v; v.f = f;
    unsigned u = v.u + 0x7FFFu + ((v.u >> 16) & 1u);
    return (unsigned short)(u >> 16);
}
__device__ __forceinline__ float bf2f(unsigned short u) {
    union { unsigned u; float f; } v; v.u = ((unsigned)u) << 16;
    return v.f;
}

__device__ __forceinline__ bf16x8 pack8(float4 a, float4 b) {
    bf16x8 r;
    r[0] = (short)f2bf(a.x); r[1] = (short)f2bf(a.y);
    r[2] = (short)f2bf(a.z); r[3] = (short)f2bf(a.w);
    r[4] = (short)f2bf(b.x); r[5] = (short)f2bf(b.y);
    r[6] = (short)f2bf(b.z); r[7] = (short)f2bf(b.w);
    return r;
}

// ---------------- weight conversion + softmax filters (fused) ----------------
__global__ void wconv_kernel(const float* __restrict__ Ws, const float* __restrict__ w1,
                             const float* __restrict__ conv_w,
                             unsigned short* __restrict__ Wsb, unsigned short* __restrict__ w1b,
                             float* __restrict__ filt) {
    int i = blockIdx.x * 256 + threadIdx.x;
    if (i < LAY * CCH) {                           // 4 threads of block 0 do softmax
        int g = i;
        float m = -1e30f;
        for (int j = 0; j < ETY; ++j) m = fmaxf(m, conv_w[g * ETY + j]);
        float e[ETY], s = 0.f;
        for (int j = 0; j < ETY; ++j) { e[j] = __expf(conv_w[g * ETY + j] - m); s += e[j]; }
        float inv = 1.f / s;
        for (int j = 0; j < ETY; ++j) filt[g * ETY + j] = e[j] * inv;
    }
    if (i < CCH * WOUT * WIN) {
        int c = i / (WOUT * WIN);
        int r = i - c * WOUT * WIN;
        int n = r / WIN;
        int k = r - n * WIN;
        Wsb[i] = f2bf(Ws[((size_t)c * WIN + k) * WOUT + n]);
    }
    if (i < WOUT * (CCH * WOUT)) {
        int n = i / (CCH * WOUT);
        int k = i - n * (CCH * WOUT);
        w1b[i] = f2bf(w1[(size_t)k * WOUT + n]);
    }
}

// ---------------- Xpb[n][d][c] = (X @ Ws[c])[n][d] bf16 interleaved ----------------
__global__ void proj_kernel(const float* __restrict__ X, const unsigned short* __restrict__ Wsb,
                            unsigned short* __restrict__ Xpb) {
    const int tid  = threadIdx.x;
    const int lane = tid & 63;
    const int wv   = tid >> 6;
    const int row0 = blockIdx.x * 64 + wv * 16;
    const int ar   = lane & 15;
    const int kg   = lane >> 4;
    int arow = row0 + ar; if (arow >= NN) arow = NN - 1;
    const float* xrow = X + (size_t)arow * WIN + kg * 8;

    f32x4 acc[2][8];
#pragma unroll
    for (int c = 0; c < 2; ++c)
#pragma unroll
        for (int nt = 0; nt < 8; ++nt) acc[c][nt] = (f32x4){0.f, 0.f, 0.f, 0.f};

#pragma unroll
    for (int kk = 0; kk < 8; ++kk) {
        float4 a0 = *(const float4*)(xrow + kk * 32);
        float4 a1 = *(const float4*)(xrow + kk * 32 + 4);
        bf16x8 af = pack8(a0, a1);
#pragma unroll
        for (int c = 0; c < 2; ++c)
#pragma unroll
            for (int nt = 0; nt < 8; ++nt) {
                const bf16x8 bfm = *(const bf16x8*)(Wsb + (size_t)c * WOUT * WIN +
                                                    (size_t)(nt * 16 + ar) * WIN + kk * 32 + kg * 8);
                acc[c][nt] = __builtin_amdgcn_mfma_f32_16x16x32_bf16(af, bfm, acc[c][nt], 0, 0, 0);
            }
    }
#pragma unroll
    for (int nt = 0; nt < 8; ++nt) {
#pragma unroll
        for (int q = 0; q < 4; ++q) {
            int r = row0 + kg * 4 + q;
            if (r < NN) {
                int col = nt * 16 + ar;
                ushort2 w;
                w.x = f2bf(acc[0][nt][q]);
                w.y = f2bf(acc[1][nt][q]);
                *(ushort2*)(Xpb + (size_t)r * (WOUT * CCH) + col * 2) = w;
            }
        }
    }
}

// ---------------- Phase A: bucket edges by row>>7 (2D grid: y = edge type) ----------------
__global__ void __launch_bounds__(256) bucket_kernel(const int* __restrict__ edge_index,
                                                     const float* __restrict__ edge_value,
                                                     int* __restrict__ bcur, int2* __restrict__ rec) {
    __shared__ int hist[NBUCK];
    __shared__ int start_s[NBUCK];
    const int tid = threadIdx.x;
    const int j = blockIdx.y;
    const int i0 = blockIdx.x * ACHUNK;
    int i1 = i0 + ACHUNK; if (i1 > NE) i1 = NE;
    const int* rows = edge_index + (size_t)j * 2 * NE;
    const int* cols = rows + NE;
    const float* evs = edge_value + (size_t)j * NE;
    for (int t = tid; t < NBUCK; t += 256) hist[t] = 0;
    __syncthreads();
    for (int i = i0 + tid; i < i1; i += 256)
        atomicAdd(&hist[rows[i] >> BSHIFT], 1);
    __syncthreads();
    for (int t = tid; t < NBUCK; t += 256) {
        int h = hist[t];
        start_s[t] = h ? atomicAdd(&bcur[t], h) : 0;
        hist[t] = 0;
    }
    __syncthreads();
    for (int i = i0 + tid; i < i1; i += 256) {
        int row = rows[i];
        int col = cols[i];
        int bk = row >> BSHIFT;
        int p = start_s[bk] + atomicAdd(&hist[bk], 1);
        if (p < BCAP)
            rec[(size_t)bk * BCAP + p] =
                make_int2(col | (j << 17) | ((row & (BNODES - 1)) << 20), __float_as_int(evs[i]));
    }
}

// ---------------- Phase B: per-bucket LDS sort + emit packed {col, bf16x2 w} per layer ----------------
__global__ void __launch_bounds__(256) sortb_kernel(const int2* __restrict__ rec,
                                                    const int* __restrict__ bcur,
                                                    const float* __restrict__ filt,
                                                    int2* __restrict__ ew0F, int2* __restrict__ ew1F,
                                                    int* __restrict__ baseF, int* __restrict__ cntF) {
    __shared__ int nh[BNODES];
    __shared__ int nb[BNODES + 1];
    __shared__ int2 srec[BCAP];
    __shared__ float fl[4 * ETY];
    const int b = blockIdx.x;
    const int tid = threadIdx.x;
    int cnt = bcur[b]; if (cnt > BCAP) cnt = BCAP;
    if (tid < BNODES) nh[tid] = 0;
    if (tid < 4 * ETY) fl[tid] = filt[tid];
    __syncthreads();
    const int2* rb = rec + (size_t)b * BCAP;
    for (int k = tid; k < cnt; k += 256) {
        int r = (rb[k].x >> 20) & (BNODES - 1);
        atomicAdd(&nh[r], 1);
    }
    __syncthreads();
    if (tid < BNODES) nb[tid + 1] = nh[tid];
    if (tid == 0) nb[0] = 0;
    __syncthreads();
    for (int off = 1; off < BNODES; off <<= 1) {
        int v = 0;
        if (tid < BNODES) { v = nb[tid + 1]; if (tid + 1 > off) v += nb[tid + 1 - off]; }
        __syncthreads();
        if (tid < BNODES) nb[tid + 1] = v;
        __syncthreads();
    }
    if (tid < BNODES) nh[tid] = 0;
    __syncthreads();
    for (int k = tid; k < cnt; k += 256) {
        int2 R = rb[k];
        int r = (R.x >> 20) & (BNODES - 1);
        int p = nb[r] + atomicAdd(&nh[r], 1);
        srec[p] = R;
    }
    __syncthreads();
    const size_t g0 = (size_t)b * BCAP;
    for (int k = tid; k < cnt; k += 256) {
        int2 R = srec[k];
        int col = R.x & 0x1FFFF;
        int j = (R.x >> 17) & 7;
        float ev = __int_as_float(R.y);
        int2 E0, E1;
        E0.x = col;
        E0.y = (int)((unsigned)f2bf(fl[j] * ev) | ((unsigned)f2bf(fl[ETY + j] * ev) << 16));
        E1.x = col;
        E1.y = (int)((unsigned)f2bf(fl[2 * ETY + j] * ev) | ((unsigned)f2bf(fl[3 * ETY + j] * ev) << 16));
        ew0F[g0 + k] = E0;
        ew1F[g0 + k] = E1;
    }
    if (tid < BNODES) {
        int n = b * BNODES + tid;
        if (n < NN) {
            baseF[n] = (int)(g0 + nb[tid]);
            cntF[n]  = nb[tid + 1] - nb[tid];
        }
    }
}

// ---------------- gather: one wave per node, packed scalar metadata, 8-deep gather MLP ----------------
__global__ void gather_kernel(const unsigned short* __restrict__ Hin, unsigned short* __restrict__ Hnew,
                              const int* __restrict__ base, const int* __restrict__ cnt,
                              const int2* __restrict__ ewF) {
    const int lane = threadIdx.x & 63;
    const int wib  = threadIdx.x >> 6;
    int n0 = blockIdx.x * 4 + wib;
    if (n0 >= NN) return;
    const int n = __builtin_amdgcn_readfirstlane(n0);   // force SGPR -> scalar loads below
    const unsigned short* hp = Hin + lane * 4;
    float a0 = 0.f, a1 = 0.f, a2 = 0.f, a3 = 0.f;
    const int kb = __builtin_amdgcn_readfirstlane(base[n]);
    const int ce = __builtin_amdgcn_readfirstlane(cnt[n]);
    const int e = kb + ce;
    for (int k = kb; k < e; k += 8) {
        int2 es[8];
#pragma unroll
        for (int u = 0; u < 8; ++u) {
            int ku = k + u;
            es[u] = ewF[ku < e ? ku : e - 1];            // uniform (scalar) 8B load
        }
        ushort4 vs[8];
#pragma unroll
        for (int u = 0; u < 8; ++u)                      // 8 independent gathers in flight
            vs[u] = *(const ushort4*)(hp + (size_t)es[u].x * (WOUT * CCH));
#pragma unroll
        for (int u = 0; u < 8; ++u) {
            float w0 = bf2f((unsigned short)(es[u].y & 0xFFFF));
            float w1 = bf2f((unsigned short)(((unsigned)es[u].y) >> 16));
            if (k + u >= e) { w0 = 0.f; w1 = 0.f; }
            a0 = fmaf(w0, bf2f(vs[u].x), a0);
            a1 = fmaf(w1, bf2f(vs[u].y), a1);
            a2 = fmaf(w0, bf2f(vs[u].z), a2);
            a3 = fmaf(w1, bf2f(vs[u].w), a3);
        }
    }
    ushort4 r4;
    r4.x = f2bf(a0); r4.y = f2bf(a1); r4.z = f2bf(a2); r4.w = f2bf(a3);
    *(ushort4*)(Hnew + (size_t)n * (WOUT * CCH) + lane * 4) = r4;
}

// ---------------- fused lin1+lin2 via bf16 MFMA, interleaved bf16 inputs ----------------
__global__ void lin_kernel(const unsigned short* __restrict__ Xpb, const unsigned short* __restrict__ Hb,
                           const unsigned short* __restrict__ w1b, const float* __restrict__ b1,
                           const float* __restrict__ w2, const float* __restrict__ b2,
                           float* __restrict__ out) {
    const int tid  = threadIdx.x;
    const int lane = tid & 63;
    const int wv   = tid >> 6;
    const int row0 = blockIdx.x * 64 + wv * 16;
    const int ar   = lane & 15;
    const int kg   = lane >> 4;
    int arow = row0 + ar; if (arow >= NN) arow = NN - 1;
    const unsigned short* xr = Xpb + (size_t)arow * (WOUT * CCH);
    const unsigned short* hr = Hb  + (size_t)arow * (WOUT * CCH);

    f32x4 acc[8];
#pragma unroll
    for (int nt = 0; nt < 8; ++nt) acc[nt] = (f32x4){0.f, 0.f, 0.f, 0.f};

    bf16x8 af1s[4];
#pragma unroll
    for (int kk = 0; kk < 4; ++kk) {
        const int d = kk * 32 + kg * 8;
        bf16x8 af0, af1;
#pragma unroll
        for (int t = 0; t < 4; ++t) {
            ushort4 xu = *(const ushort4*)(xr + 2 * d + 4 * t);
            ushort4 hu = *(const ushort4*)(hr + 2 * d + 4 * t);
            float v00 = fmaxf(0.1f * bf2f(xu.x) + 0.9f * bf2f(hu.x), 0.f);
            float v01 = fmaxf(0.1f * bf2f(xu.y) + 0.9f * bf2f(hu.y), 0.f);
            float v10 = fmaxf(0.1f * bf2f(xu.z) + 0.9f * bf2f(hu.z), 0.f);
            float v11 = fmaxf(0.1f * bf2f(xu.w) + 0.9f * bf2f(hu.w), 0.f);
            af0[2 * t]     = (short)f2bf(v00);
            af0[2 * t + 1] = (short)f2bf(v10);
            af1[2 * t]     = (short)f2bf(v01);
            af1[2 * t + 1] = (short)f2bf(v11);
        }
        af1s[kk] = af1;
        const int k0 = kk * 32 + kg * 8;
#pragma unroll
        for (int nt = 0; nt < 8; ++nt) {
            const bf16x8 bfm = *(const bf16x8*)(w1b + (size_t)(nt * 16 + ar) * (CCH * WOUT) + k0);
            acc[nt] = __builtin_amdgcn_mfma_f32_16x16x32_bf16(af0, bfm, acc[nt], 0, 0, 0);
        }
    }
#pragma unroll
    for (int kk = 4; kk < 8; ++kk) {
        const int k0 = kk * 32 + kg * 8;
        const bf16x8 af = af1s[kk - 4];
#pragma unroll
        for (int nt = 0; nt < 8; ++nt) {
            const bf16x8 bfm = *(const bf16x8*)(w1b + (size_t)(nt * 16 + ar) * (CCH * WOUT) + k0);
            acc[nt] = __builtin_amdgcn_mfma_f32_16x16x32_bf16(af, bfm, acc[nt], 0, 0, 0);
        }
    }

    float b1v[8], w2v[8][NCLS];
#pragma unroll
    for (int nt = 0; nt < 8; ++nt) {
        int col = nt * 16 + ar;
        b1v[nt] = b1[col];
#pragma unroll
        for (int m = 0; m < NCLS; ++m) w2v[nt][m] = w2[col * NCLS + m];
    }
#pragma unroll
    for (int q = 0; q < 4; ++q) {
        float pm[NCLS] = {0.f, 0.f, 0.f};
#pragma unroll
        for (int nt = 0; nt < 8; ++nt) {
            float h = acc[nt][q] + b1v[nt];
#pragma unroll
            for (int m = 0; m < NCLS; ++m) pm[m] = fmaf(h, w2v[nt][m], pm[m]);
        }
#pragma unroll
        for (int m = 0; m < NCLS; ++m) {
            pm[m] += __shfl_xor(pm[m], 1);
            pm[m] += __shfl_xor(pm[m], 2);
            pm[m] += __shfl_xor(pm[m], 4);
            pm[m] += __shfl_xor(pm[m], 8);
        }
        int r = row0 + kg * 4 + q;
        if (ar == 0 && r < NN) {
            out[(size_t)r * NCLS + 0] = pm[0] + b2[0];
            out[(size_t)r * NCLS + 1] = pm[1] + b2[1];
            out[(size_t)r * NCLS + 2] = pm[2] + b2[2];
        }
    }
}

extern "C" void kernel_launch(void* const* d_in, const int* in_sizes, int n_in,
                              void* d_out, int out_size, void* d_ws, size_t ws_size,
                              hipStream_t stream) {
    const int*   edge_index = (const int*)d_in[0];
    const float* edge_value = (const float*)d_in[1];
    const float* X          = (const float*)d_in[2];
    const float* Ws         = (const float*)d_in[3];
    const float* conv_w     = (const float*)d_in[4];
    const float* lin1_w     = (const float*)d_in[5];
    const float* lin1_b     = (const float*)d_in[6];
    const float* lin2_w     = (const float*)d_in[7];
    const float* lin2_b     = (const float*)d_in[8];
    float* out = (float*)d_out;

    const size_t CNU  = (size_t)NN * WOUT * CCH;
    const size_t SLOT = (size_t)NBUCK * BCAP;
    unsigned short* Xpb = (unsigned short*)d_ws;           // [N][128][2] bf16
    unsigned short* Ab  = Xpb + CNU;
    unsigned short* Bb  = Ab + CNU;
    float*  filt  = (float*)(Bb + CNU);                    // [L][C][ETY] pad 32
    int*    bcur  = (int*)(filt + 32);                     // [NBUCK]
    int*    baseF = bcur + NBUCK;                          // [NN]
    int*    cntF  = baseF + NN;                            // [NN]
    int2*   rec   = (int2*)(cntF + NN);                    // [SLOT]
    int2*   ew0F  = rec + SLOT;                            // [SLOT] {col, bf16x2 w}
    int2*   ew1F  = ew0F + SLOT;                           // [SLOT]
    unsigned short* Wsb = (unsigned short*)(ew1F + SLOT);  // [C][128][256] bf16
    unsigned short* w1b = Wsb + (size_t)CCH * WOUT * WIN;  // [128][256] bf16

    hipMemsetAsync(bcur, 0, NBUCK * sizeof(int), stream);

    wconv_kernel<<<(CCH * WOUT * WIN + 255) / 256, 256, 0, stream>>>(Ws, lin1_w, conv_w, Wsb, w1b, filt);

    proj_kernel<<<(NN + 63) / 64, 256, 0, stream>>>(X, Wsb, Xpb);

    dim3 bg(ABLK, ETY);
    bucket_kernel<<<bg, 256, 0, stream>>>(edge_index, edge_value, bcur, rec);
    sortb_kernel<<<NBUCK, 256, 0, stream>>>(rec, bcur, filt, ew0F, ew1F, baseF, cntF);

    const int gblocks = (NN + 3) / 4;
    gather_kernel<<<gblocks, 256, 0, stream>>>(Xpb, Ab, baseF, cntF, ew0F);
    gather_kernel<<<gblocks, 256, 0, stream>>>(Ab, Bb, baseF, cntF, ew1F);

    lin_kernel<<<(NN + 63) / 64, 256, 0, stream>>>(Xpb, Bb, w1b, lin1_b, lin2_w, lin2_b, out);
}

// Round 9
// 573.843 us; speedup vs baseline: 16.4326x; 1.1181x over previous
//
#include <hip/hip_runtime.h>

#define NN   100000   // num_nodes
#define ETY  5        // edge types
#define NE   500000   // edges per type
#define WIN  256
#define WOUT 128
#define CCH  2
#define LAY  2
#define NCLS 3

#define NTOT   (ETY * NE)             // 2500000 edges total
#define BSHIFT 7                      // 128 nodes per bucket
#define BNODES 128
#define NBUCK  ((NN + BNODES - 1) / BNODES)   // 782
#define BCAP   4096                   // capacity per bucket (mean ~3200)
#define ACHUNK 8192
#define ABLK   ((NE + ACHUNK - 1) / ACHUNK)   // 62

typedef __attribute__((ext_vector_type(8))) short bf16x8;
typedef __attribute__((ext_vector_type(8))) unsigned short u16x8;
typedef __attribute__((ext_vector_type(4))) float f32x4;

__device__ __forceinline__ unsigned short f2bf(float f) {
    union { float f; unsigned u; } v; v.f = f;
    unsigned u = v.u + 0x7FFFu + ((v.u >> 16) & 1u);
    return (unsigned short)(u >> 16);
}
__device__ __forceinline__ float bf2f(unsigned short u) {
    union { unsigned u; float f; } v; v.u = ((unsigned)u) << 16;
    return v.f;
}

__device__ __forceinline__ bf16x8 pack8(float4 a, float4 b) {
    bf16x8 r;
    r[0] = (short)f2bf(a.x); r[1] = (short)f2bf(a.y);
    r[2] = (short)f2bf(a.z); r[3] = (short)f2bf(a.w);
    r[4] = (short)f2bf(b.x); r[5] = (short)f2bf(b.y);
    r[6] = (short)f2bf(b.z); r[7] = (short)f2bf(b.w);
    return r;
}

// ---------------- weight conversion + softmax filters (fused) ----------------
__global__ void wconv_kernel(const float* __restrict__ Ws, const float* __restrict__ w1,
                             const float* __restrict__ conv_w,
                             unsigned short* __restrict__ Wsb, unsigned short* __restrict__ w1b,
                             float* __restrict__ filt) {
    int i = blockIdx.x * 256 + threadIdx.x;
    if (i < LAY * CCH) {
        int g = i;
        float m = -1e30f;
        for (int j = 0; j < ETY; ++j) m = fmaxf(m, conv_w[g * ETY + j]);
        float e[ETY], s = 0.f;
        for (int j = 0; j < ETY; ++j) { e[j] = __expf(conv_w[g * ETY + j] - m); s += e[j]; }
        float inv = 1.f / s;
        for (int j = 0; j < ETY; ++j) filt[g * ETY + j] = e[j] * inv;
    }
    if (i < CCH * WOUT * WIN) {
        int c = i / (WOUT * WIN);
        int r = i - c * WOUT * WIN;
        int n = r / WIN;
        int k = r - n * WIN;
        Wsb[i] = f2bf(Ws[((size_t)c * WIN + k) * WOUT + n]);
    }
    if (i < WOUT * (CCH * WOUT)) {
        int n = i / (CCH * WOUT);
        int k = i - n * (CCH * WOUT);
        w1b[i] = f2bf(w1[(size_t)k * WOUT + n]);
    }
}

// ---------------- Xpb[n][d][c] = (X @ Ws[c])[n][d] bf16 interleaved ----------------
// 4 waves x 32 rows = 128 rows/block; each B-fragment feeds 2 MFMAs (2 row-tiles)
__global__ void __launch_bounds__(256) proj_kernel(const float* __restrict__ X,
                                                   const unsigned short* __restrict__ Wsb,
                                                   unsigned short* __restrict__ Xpb) {
    const int tid  = threadIdx.x;
    const int lane = tid & 63;
    const int wv   = tid >> 6;
    const int row0 = blockIdx.x * 128 + wv * 32;
    const int ar   = lane & 15;
    const int kg   = lane >> 4;
    int arow0 = row0 + ar;      if (arow0 >= NN) arow0 = NN - 1;
    int arow1 = row0 + 16 + ar; if (arow1 >= NN) arow1 = NN - 1;
    const float* xr0 = X + (size_t)arow0 * WIN + kg * 8;
    const float* xr1 = X + (size_t)arow1 * WIN + kg * 8;

    f32x4 acc[2][2][8];          // [ch][row-tile][nt]
#pragma unroll
    for (int c = 0; c < 2; ++c)
#pragma unroll
        for (int rt = 0; rt < 2; ++rt)
#pragma unroll
            for (int nt = 0; nt < 8; ++nt) acc[c][rt][nt] = (f32x4){0.f, 0.f, 0.f, 0.f};

#pragma unroll
    for (int kk = 0; kk < 8; ++kk) {
        float4 a00 = *(const float4*)(xr0 + kk * 32);
        float4 a01 = *(const float4*)(xr0 + kk * 32 + 4);
        float4 a10 = *(const float4*)(xr1 + kk * 32);
        float4 a11 = *(const float4*)(xr1 + kk * 32 + 4);
        bf16x8 af0 = pack8(a00, a01);
        bf16x8 af1 = pack8(a10, a11);
#pragma unroll
        for (int c = 0; c < 2; ++c)
#pragma unroll
            for (int nt = 0; nt < 8; ++nt) {
                const bf16x8 bfm = *(const bf16x8*)(Wsb + (size_t)c * WOUT * WIN +
                                                    (size_t)(nt * 16 + ar) * WIN + kk * 32 + kg * 8);
                acc[c][0][nt] = __builtin_amdgcn_mfma_f32_16x16x32_bf16(af0, bfm, acc[c][0][nt], 0, 0, 0);
                acc[c][1][nt] = __builtin_amdgcn_mfma_f32_16x16x32_bf16(af1, bfm, acc[c][1][nt], 0, 0, 0);
            }
    }
#pragma unroll
    for (int rt = 0; rt < 2; ++rt) {
#pragma unroll
        for (int nt = 0; nt < 8; ++nt) {
#pragma unroll
            for (int q = 0; q < 4; ++q) {
                int r = row0 + rt * 16 + kg * 4 + q;
                if (r < NN) {
                    int col = nt * 16 + ar;
                    ushort2 w;
                    w.x = f2bf(acc[0][rt][nt][q]);
                    w.y = f2bf(acc[1][rt][nt][q]);
                    *(ushort2*)(Xpb + (size_t)r * (WOUT * CCH) + col * 2) = w;
                }
            }
        }
    }
}

// ---------------- Phase A: bucket edges by row>>7 (2D grid: y = edge type), int4 loads ----------------
__global__ void __launch_bounds__(256) bucket_kernel(const int* __restrict__ edge_index,
                                                     const float* __restrict__ edge_value,
                                                     int* __restrict__ bcur, int2* __restrict__ rec) {
    __shared__ int hist[NBUCK];
    __shared__ int start_s[NBUCK];
    const int tid = threadIdx.x;
    const int j = blockIdx.y;
    const int i0 = blockIdx.x * ACHUNK;
    int i1 = i0 + ACHUNK; if (i1 > NE) i1 = NE;   // NE % 4 == 0
    const int* rows = edge_index + (size_t)j * 2 * NE;
    const int* cols = rows + NE;
    const float* evs = edge_value + (size_t)j * NE;
    for (int t = tid; t < NBUCK; t += 256) hist[t] = 0;
    __syncthreads();
    for (int i = i0 + tid * 4; i < i1; i += 1024) {
        int4 r4 = *(const int4*)(rows + i);
        atomicAdd(&hist[r4.x >> BSHIFT], 1);
        atomicAdd(&hist[r4.y >> BSHIFT], 1);
        atomicAdd(&hist[r4.z >> BSHIFT], 1);
        atomicAdd(&hist[r4.w >> BSHIFT], 1);
    }
    __syncthreads();
    for (int t = tid; t < NBUCK; t += 256) {
        int h = hist[t];
        start_s[t] = h ? atomicAdd(&bcur[t], h) : 0;
        hist[t] = 0;
    }
    __syncthreads();
    for (int i = i0 + tid * 4; i < i1; i += 1024) {
        int4 r4 = *(const int4*)(rows + i);
        int4 c4 = *(const int4*)(cols + i);
        float4 e4 = *(const float4*)(evs + i);
#pragma unroll
        for (int u = 0; u < 4; ++u) {
            int row = (u == 0) ? r4.x : (u == 1) ? r4.y : (u == 2) ? r4.z : r4.w;
            int col = (u == 0) ? c4.x : (u == 1) ? c4.y : (u == 2) ? c4.z : c4.w;
            float ev = (u == 0) ? e4.x : (u == 1) ? e4.y : (u == 2) ? e4.z : e4.w;
            int bk = row >> BSHIFT;
            int p = start_s[bk] + atomicAdd(&hist[bk], 1);
            if (p < BCAP)
                rec[(size_t)bk * BCAP + p] =
                    make_int2(col | (j << 17) | ((row & (BNODES - 1)) << 20), __float_as_int(ev));
        }
    }
}

// ---------------- Phase B: per-bucket LDS sort + emit packed {col, bf16x2 w} per layer ----------------
__global__ void __launch_bounds__(256) sortb_kernel(const int2* __restrict__ rec,
                                                    const int* __restrict__ bcur,
                                                    const float* __restrict__ filt,
                                                    int2* __restrict__ ew0F, int2* __restrict__ ew1F,
                                                    int* __restrict__ baseF, int* __restrict__ cntF) {
    __shared__ int nh[BNODES];
    __shared__ int nb[BNODES + 1];
    __shared__ int2 srec[BCAP];
    __shared__ float fl[4 * ETY];
    const int b = blockIdx.x;
    const int tid = threadIdx.x;
    int cnt = bcur[b]; if (cnt > BCAP) cnt = BCAP;
    if (tid < BNODES) nh[tid] = 0;
    if (tid < 4 * ETY) fl[tid] = filt[tid];
    __syncthreads();
    const int2* rb = rec + (size_t)b * BCAP;
    for (int k = tid; k < cnt; k += 256) {
        int r = (rb[k].x >> 20) & (BNODES - 1);
        atomicAdd(&nh[r], 1);
    }
    __syncthreads();
    if (tid < BNODES) nb[tid + 1] = nh[tid];
    if (tid == 0) nb[0] = 0;
    __syncthreads();
    for (int off = 1; off < BNODES; off <<= 1) {
        int v = 0;
        if (tid < BNODES) { v = nb[tid + 1]; if (tid + 1 > off) v += nb[tid + 1 - off]; }
        __syncthreads();
        if (tid < BNODES) nb[tid + 1] = v;
        __syncthreads();
    }
    if (tid < BNODES) nh[tid] = 0;
    __syncthreads();
    for (int k = tid; k < cnt; k += 256) {
        int2 R = rb[k];
        int r = (R.x >> 20) & (BNODES - 1);
        int p = nb[r] + atomicAdd(&nh[r], 1);
        srec[p] = R;
    }
    __syncthreads();
    const size_t g0 = (size_t)b * BCAP;
    for (int k = tid; k < cnt; k += 256) {
        int2 R = srec[k];
        int col = R.x & 0x1FFFF;
        int j = (R.x >> 17) & 7;
        float ev = __int_as_float(R.y);
        int2 E0, E1;
        E0.x = col;
        E0.y = (int)((unsigned)f2bf(fl[j] * ev) | ((unsigned)f2bf(fl[ETY + j] * ev) << 16));
        E1.x = col;
        E1.y = (int)((unsigned)f2bf(fl[2 * ETY + j] * ev) | ((unsigned)f2bf(fl[3 * ETY + j] * ev) << 16));
        ew0F[g0 + k] = E0;
        ew1F[g0 + k] = E1;
    }
    if (tid < BNODES) {
        int n = b * BNODES + tid;
        if (n < NN) {
            baseF[n] = (int)(g0 + nb[tid]);
            cntF[n]  = nb[tid + 1] - nb[tid];
        }
    }
}

// ---------------- gather: one wave per node, packed scalar metadata, 8-deep gather MLP ----------------
__global__ void gather_kernel(const unsigned short* __restrict__ Hin, unsigned short* __restrict__ Hnew,
                              const int* __restrict__ base, const int* __restrict__ cnt,
                              const int2* __restrict__ ewF) {
    const int lane = threadIdx.x & 63;
    const int wib  = threadIdx.x >> 6;
    int n0 = blockIdx.x * 4 + wib;
    if (n0 >= NN) return;
    const int n = __builtin_amdgcn_readfirstlane(n0);
    const unsigned short* hp = Hin + lane * 4;
    float a0 = 0.f, a1 = 0.f, a2 = 0.f, a3 = 0.f;
    const int kb = __builtin_amdgcn_readfirstlane(base[n]);
    const int ce = __builtin_amdgcn_readfirstlane(cnt[n]);
    const int e = kb + ce;
    for (int k = kb; k < e; k += 8) {
        int2 es[8];
#pragma unroll
        for (int u = 0; u < 8; ++u) {
            int ku = k + u;
            es[u] = ewF[ku < e ? ku : e - 1];
        }
        ushort4 vs[8];
#pragma unroll
        for (int u = 0; u < 8; ++u)
            vs[u] = *(const ushort4*)(hp + (size_t)es[u].x * (WOUT * CCH));
#pragma unroll
        for (int u = 0; u < 8; ++u) {
            float w0 = bf2f((unsigned short)(es[u].y & 0xFFFF));
            float w1 = bf2f((unsigned short)(((unsigned)es[u].y) >> 16));
            if (k + u >= e) { w0 = 0.f; w1 = 0.f; }
            a0 = fmaf(w0, bf2f(vs[u].x), a0);
            a1 = fmaf(w1, bf2f(vs[u].y), a1);
            a2 = fmaf(w0, bf2f(vs[u].z), a2);
            a3 = fmaf(w1, bf2f(vs[u].w), a3);
        }
    }
    ushort4 r4;
    r4.x = f2bf(a0); r4.y = f2bf(a1); r4.z = f2bf(a2); r4.w = f2bf(a3);
    *(ushort4*)(Hnew + (size_t)n * (WOUT * CCH) + lane * 4) = r4;
}

// ---------------- fused lin1+lin2 via bf16 MFMA, 16B A-operand loads ----------------
__global__ void lin_kernel(const unsigned short* __restrict__ Xpb, const unsigned short* __restrict__ Hb,
                           const unsigned short* __restrict__ w1b, const float* __restrict__ b1,
                           const float* __restrict__ w2, const float* __restrict__ b2,
                           float* __restrict__ out) {
    const int tid  = threadIdx.x;
    const int lane = tid & 63;
    const int wv   = tid >> 6;
    const int row0 = blockIdx.x * 64 + wv * 16;
    const int ar   = lane & 15;
    const int kg   = lane >> 4;
    int arow = row0 + ar; if (arow >= NN) arow = NN - 1;
    const unsigned short* xr = Xpb + (size_t)arow * (WOUT * CCH);
    const unsigned short* hr = Hb  + (size_t)arow * (WOUT * CCH);

    f32x4 acc[8];
#pragma unroll
    for (int nt = 0; nt < 8; ++nt) acc[nt] = (f32x4){0.f, 0.f, 0.f, 0.f};

    bf16x8 af1s[4];
#pragma unroll
    for (int kk = 0; kk < 4; ++kk) {
        const int d = kk * 32 + kg * 8;
        unsigned short xs[16], hs[16];
        *(u16x8*)&xs[0] = *(const u16x8*)(xr + 2 * d);
        *(u16x8*)&xs[8] = *(const u16x8*)(xr + 2 * d + 8);
        *(u16x8*)&hs[0] = *(const u16x8*)(hr + 2 * d);
        *(u16x8*)&hs[8] = *(const u16x8*)(hr + 2 * d + 8);
        bf16x8 af0, af1;
#pragma unroll
        for (int t = 0; t < 8; ++t) {
            float v0 = fmaxf(0.1f * bf2f(xs[2 * t])     + 0.9f * bf2f(hs[2 * t]), 0.f);      // feat d+t, c0
            float v1 = fmaxf(0.1f * bf2f(xs[2 * t + 1]) + 0.9f * bf2f(hs[2 * t + 1]), 0.f);  // feat d+t, c1
            af0[t] = (short)f2bf(v0);
            af1[t] = (short)f2bf(v1);
        }
        af1s[kk] = af1;
        const int k0 = kk * 32 + kg * 8;
#pragma unroll
        for (int nt = 0; nt < 8; ++nt) {
            const bf16x8 bfm = *(const bf16x8*)(w1b + (size_t)(nt * 16 + ar) * (CCH * WOUT) + k0);
            acc[nt] = __builtin_amdgcn_mfma_f32_16x16x32_bf16(af0, bfm, acc[nt], 0, 0, 0);
        }
    }
#pragma unroll
    for (int kk = 4; kk < 8; ++kk) {
        const int k0 = kk * 32 + kg * 8;
        const bf16x8 af = af1s[kk - 4];
#pragma unroll
        for (int nt = 0; nt < 8; ++nt) {
            const bf16x8 bfm = *(const bf16x8*)(w1b + (size_t)(nt * 16 + ar) * (CCH * WOUT) + k0);
            acc[nt] = __builtin_amdgcn_mfma_f32_16x16x32_bf16(af, bfm, acc[nt], 0, 0, 0);
        }
    }

    float b1v[8], w2v[8][NCLS];
#pragma unroll
    for (int nt = 0; nt < 8; ++nt) {
        int col = nt * 16 + ar;
        b1v[nt] = b1[col];
#pragma unroll
        for (int m = 0; m < NCLS; ++m) w2v[nt][m] = w2[col * NCLS + m];
    }
#pragma unroll
    for (int q = 0; q < 4; ++q) {
        float pm[NCLS] = {0.f, 0.f, 0.f};
#pragma unroll
        for (int nt = 0; nt < 8; ++nt) {
            float h = acc[nt][q] + b1v[nt];
#pragma unroll
            for (int m = 0; m < NCLS; ++m) pm[m] = fmaf(h, w2v[nt][m], pm[m]);
        }
#pragma unroll
        for (int m = 0; m < NCLS; ++m) {
            pm[m] += __shfl_xor(pm[m], 1);
            pm[m] += __shfl_xor(pm[m], 2);
            pm[m] += __shfl_xor(pm[m], 4);
            pm[m] += __shfl_xor(pm[m], 8);
        }
        int r = row0 + kg * 4 + q;
        if (ar == 0 && r < NN) {
            out[(size_t)r * NCLS + 0] = pm[0] + b2[0];
            out[(size_t)r * NCLS + 1] = pm[1] + b2[1];
            out[(size_t)r * NCLS + 2] = pm[2] + b2[2];
        }
    }
}

extern "C" void kernel_launch(void* const* d_in, const int* in_sizes, int n_in,
                              void* d_out, int out_size, void* d_ws, size_t ws_size,
                              hipStream_t stream) {
    const int*   edge_index = (const int*)d_in[0];
    const float* edge_value = (const float*)d_in[1];
    const float* X          = (const float*)d_in[2];
    const float* Ws         = (const float*)d_in[3];
    const float* conv_w     = (const float*)d_in[4];
    const float* lin1_w     = (const float*)d_in[5];
    const float* lin1_b     = (const float*)d_in[6];
    const float* lin2_w     = (const float*)d_in[7];
    const float* lin2_b     = (const float*)d_in[8];
    float* out = (float*)d_out;

    const size_t CNU  = (size_t)NN * WOUT * CCH;
    const size_t SLOT = (size_t)NBUCK * BCAP;
    unsigned short* Xpb = (unsigned short*)d_ws;           // [N][128][2] bf16
    unsigned short* Ab  = Xpb + CNU;
    unsigned short* Bb  = Ab + CNU;
    float*  filt  = (float*)(Bb + CNU);                    // [L][C][ETY] pad 32
    int*    bcur  = (int*)(filt + 32);                     // [NBUCK]
    int*    baseF = bcur + NBUCK;                          // [NN]
    int*    cntF  = baseF + NN;                            // [NN]
    int2*   rec   = (int2*)(cntF + NN);                    // [SLOT]
    int2*   ew0F  = rec + SLOT;                            // [SLOT] {col, bf16x2 w}
    int2*   ew1F  = ew0F + SLOT;                           // [SLOT]
    unsigned short* Wsb = (unsigned short*)(ew1F + SLOT);  // [C][128][256] bf16
    unsigned short* w1b = Wsb + (size_t)CCH * WOUT * WIN;  // [128][256] bf16

    hipMemsetAsync(bcur, 0, NBUCK * sizeof(int), stream);

    wconv_kernel<<<(CCH * WOUT * WIN + 255) / 256, 256, 0, stream>>>(Ws, lin1_w, conv_w, Wsb, w1b, filt);

    proj_kernel<<<(NN + 127) / 128, 256, 0, stream>>>(X, Wsb, Xpb);

    dim3 bg(ABLK, ETY);
    bucket_kernel<<<bg, 256, 0, stream>>>(edge_index, edge_value, bcur, rec);
    sortb_kernel<<<NBUCK, 256, 0, stream>>>(rec, bcur, filt, ew0F, ew1F, baseF, cntF);

    const int gblocks = (NN + 3) / 4;
    gather_kernel<<<gblocks, 256, 0, stream>>>(Xpb, Ab, baseF, cntF, ew0F);
    gather_kernel<<<gblocks, 256, 0, stream>>>(Ab, Bb, baseF, cntF, ew1F);

    lin_kernel<<<(NN + 63) / 64, 256, 0, stream>>>(Xpb, Bb, w1b, lin1_b, lin2_w, lin2_b, out);
}